// Round 8
// baseline (325.444 us; speedup 1.0000x reference)
//
#include <hip/hip_runtime.h>
#include <hip/hip_bf16.h>
#include <math.h>

#define N_NODES 50000
#define N_EDGES 800000
#define D_IN 256
#define D_HID 256
#define D_OUT 128

typedef unsigned short ushort_t;
typedef __attribute__((ext_vector_type(8))) short bf16x8;
typedef __attribute__((ext_vector_type(4))) float f32x4;
typedef __attribute__((ext_vector_type(4))) int int4v;
typedef __attribute__((ext_vector_type(2))) float f32x2;

__device__ inline ushort_t f2bf(float f) {
    __hip_bfloat16 h = __float2bfloat16(f);  // RNE
    return *reinterpret_cast<ushort_t*>(&h);
}
// bf16 pair unpack: lo = bits<<16, hi = bits&0xffff0000 (1 VALU op each)
__device__ inline float blo(unsigned u) {
    union { unsigned i; float f; } v; v.i = u << 16; return v.f;
}
__device__ inline float bhi(unsigned u) {
    union { unsigned i; float f; } v; v.i = u & 0xffff0000u; return v.f;
}
__device__ inline unsigned pack2bf(float a, float b) {
    return (unsigned)f2bf(a) | ((unsigned)f2bf(b) << 16);
}

// ================= degree =================

__global__ void k_count(const int* __restrict__ dst, int* __restrict__ degI, int e) {
    int i = blockIdx.x * 256 + threadIdx.x;
    if (i < e) atomicAdd(&degI[dst[i]], 1);
}

// ================= scan over PADDED degrees (pad to multiple of 16) =================

__global__ void k_block_sums(const int* __restrict__ degI, int* __restrict__ bsum, int n) {
    __shared__ int s[256];
    int i = blockIdx.x * 256 + threadIdx.x;
    int v = 0;
    if (i < n) v = (degI[i] + 15) & ~15;
    s[threadIdx.x] = v;
    __syncthreads();
    for (int st = 128; st > 0; st >>= 1) {
        if (threadIdx.x < st) s[threadIdx.x] += s[threadIdx.x + st];
        __syncthreads();
    }
    if (threadIdx.x == 0) bsum[blockIdx.x] = s[0];
}

__global__ void k_scan_bsums(int* __restrict__ bsum, int nb) {
    __shared__ int s[256];
    int t = threadIdx.x;
    s[t] = (t < nb) ? bsum[t] : 0;
    __syncthreads();
    for (int off = 1; off < 256; off <<= 1) {
        int v = 0;
        if (t >= off) v = s[t - off];
        __syncthreads();
        if (t >= off) s[t] += v;
        __syncthreads();
    }
    if (t < nb) bsum[t] = (t == 0) ? 0 : s[t - 1];
}

// computes offs/cursor/dinv AND fills padding slots with zero-row index
__global__ void k_scan_apply(const int* __restrict__ degI, const int* __restrict__ bsum,
                             int* __restrict__ offs, int* __restrict__ cursor,
                             float* __restrict__ dinv, int* __restrict__ ebuf, int n) {
    __shared__ int s[256];
    int t = threadIdx.x;
    int i = blockIdx.x * 256 + t;
    int deg = (i < n) ? degI[i] : 0;
    int v = (deg + 15) & ~15;
    s[t] = v;
    __syncthreads();
    for (int off = 1; off < 256; off <<= 1) {
        int u = 0;
        if (t >= off) u = s[t - off];
        __syncthreads();
        if (t >= off) s[t] += u;
        __syncthreads();
    }
    int excl = s[t] - v + bsum[blockIdx.x];
    if (i < n) {
        offs[i] = excl;
        cursor[i] = excl;
        dinv[i] = rsqrtf((float)(1 + deg));
        for (int p = excl + deg; p < excl + v; ++p) ebuf[p] = N_NODES;
        if (i == n - 1) offs[n] = excl + v;
    }
}

__global__ void k_fill(const int* __restrict__ src, const int* __restrict__ dst,
                       int* __restrict__ cursor, int* __restrict__ ebuf, int e) {
    int i = blockIdx.x * 256 + threadIdx.x;
    if (i < e) {
        int d = dst[i];
        int pos = atomicAdd(&cursor[d], 1);
        ebuf[pos] = src[i];
    }
}

// ================= weight transpose+convert + zero-row init =================

__global__ void k_convW(const float* __restrict__ W1, const float* __restrict__ W2,
                        ushort_t* __restrict__ Wt1, ushort_t* __restrict__ Wt2,
                        ushort_t* __restrict__ h1z, ushort_t* __restrict__ h2z) {
    int i = blockIdx.x * 256 + threadIdx.x;
    const int n1 = D_IN * D_HID;       // 65536
    const int n2 = D_HID * D_OUT;      // 32768
    if (i < n1) {
        int k = i / D_HID, n = i % D_HID;
        Wt1[(size_t)n * D_IN + k] = f2bf(W1[i]);
    } else if (i < n1 + n2) {
        int j = i - n1;
        int k = j / D_OUT, n = j % D_OUT;
        Wt2[(size_t)n * D_HID + k] = f2bf(W2[j]);
    } else {
        int j = i - n1 - n2;
        if (j < D_HID) h1z[j] = 0;
        else if (j < D_HID + D_OUT) h2z[j - D_HID] = 0;
    }
}

// ================= bf16 MFMA GEMM with dinv-scaled epilogue =================
// C[M,N](bf16) = (A[M,K] * Bt[N,K]^T) * dinv[row]; 128x128 tile, 4 waves, BK=32.

template <bool A_IS_BF16>
__global__ __launch_bounds__(256) void k_gemm_mfma(const void* __restrict__ Av,
                                                   const ushort_t* __restrict__ Bt,
                                                   const float* __restrict__ dinvD,
                                                   ushort_t* __restrict__ C,
                                                   int M, int K, int N) {
    __shared__ ushort_t As[128 * 40];
    __shared__ ushort_t Bs[128 * 40];

    const int t = threadIdx.x;
    const int lane = t & 63;
    const int w = t >> 6;
    const int wr = w >> 1, wc = w & 1;
    const int m0 = blockIdx.x * 128;
    const int n0 = blockIdx.y * 128;

    const int srow = t >> 1;
    const int scol = (t & 1) * 16;

    f32x4 acc[4][4];
#pragma unroll
    for (int m = 0; m < 4; ++m)
#pragma unroll
        for (int n = 0; n < 4; ++n)
#pragma unroll
            for (int i = 0; i < 4; ++i) acc[m][n][i] = 0.0f;

    for (int kt = 0; kt < K; kt += 32) {
        const int gr = m0 + srow;
        if (A_IS_BF16) {
            const ushort_t* A = (const ushort_t*)Av;
            uint4 v0 = make_uint4(0, 0, 0, 0), v1 = make_uint4(0, 0, 0, 0);
            if (gr < M) {
                const uint4* p = (const uint4*)(A + (size_t)gr * K + kt + scol);
                v0 = p[0]; v1 = p[1];
            }
            *(uint4*)&As[srow * 40 + scol] = v0;
            *(uint4*)&As[srow * 40 + scol + 8] = v1;
        } else {
            const float* A = (const float*)Av;
#pragma unroll
            for (int i = 0; i < 4; ++i) {
                float4 v = make_float4(0.f, 0.f, 0.f, 0.f);
                if (gr < M) v = *(const float4*)(A + (size_t)gr * K + kt + scol + 4 * i);
                ushort4 u;
                u.x = f2bf(v.x); u.y = f2bf(v.y); u.z = f2bf(v.z); u.w = f2bf(v.w);
                *(ushort4*)&As[srow * 40 + scol + 4 * i] = u;
            }
        }
        {
            const uint4* p = (const uint4*)(Bt + (size_t)(n0 + srow) * K + kt + scol);
            uint4 v0 = p[0], v1 = p[1];
            *(uint4*)&Bs[srow * 40 + scol] = v0;
            *(uint4*)&Bs[srow * 40 + scol + 8] = v1;
        }
        __syncthreads();

        const int kg = (lane >> 4) * 8;
        const int lr = lane & 15;
        bf16x8 a[4], b[4];
#pragma unroll
        for (int m = 0; m < 4; ++m)
            a[m] = *(const bf16x8*)&As[(wr * 64 + m * 16 + lr) * 40 + kg];
#pragma unroll
        for (int n = 0; n < 4; ++n)
            b[n] = *(const bf16x8*)&Bs[(wc * 64 + n * 16 + lr) * 40 + kg];
#pragma unroll
        for (int m = 0; m < 4; ++m)
#pragma unroll
            for (int n = 0; n < 4; ++n)
                acc[m][n] = __builtin_amdgcn_mfma_f32_16x16x32_bf16(a[m], b[n], acc[m][n], 0, 0, 0);
        __syncthreads();
    }

    const int lr = lane & 15;
    const int rg = (lane >> 4) * 4;
#pragma unroll
    for (int m = 0; m < 4; ++m) {
        const int rb = m0 + wr * 64 + m * 16 + rg;
#pragma unroll
        for (int i = 0; i < 4; ++i) {
            const int row = rb + i;
            if (row < M) {
                const float dr = dinvD[row];
#pragma unroll
                for (int n = 0; n < 4; ++n) {
                    const int col = n0 + wc * 64 + n * 16 + lr;
                    C[(size_t)row * N + col] = f2bf(acc[m][n][i] * dr);
                }
            }
        }
    }
}

// ================= sliced CSR gather (XCD-pinned slices, nt metadata) =================
// out[node][slice] = F(dinv[node] * (h'[node] + sum_e h'[src_e]) + bias)[slice]
// Slice = 32 dims = 64B = 1 cache line per edge. slice = blockIdx.x % NSLICE,
// rr block->XCD dispatch pins each 3.2MB h-slice to one XCD's L2.
// KEY (R8): ebuf index loads are NON-TEMPORAL (evict-first) and the output
// store is non-temporal, so the streams don't evict the resident h-slice.
// Index loads are 2x int4 per 8-edge batch (2 VMEM instr, not 8).
// One node per 16-lane group; no cross-lane ops, no LDS.
// MODE 0: F = relu, bf16 out. MODE 1: F = sigmoid, f32 out.

template <int DIM, int NSLICE, int MODE>
__global__ __launch_bounds__(256) void k_gather_slice(const ushort_t* __restrict__ h,
                                                      const float* __restrict__ dinv,
                                                      const int* __restrict__ offs,
                                                      const int* __restrict__ ebuf,
                                                      const float* __restrict__ bias,
                                                      void* __restrict__ outv, int n) {
    const int slice = blockIdx.x % NSLICE;
    const int node = (blockIdx.x / NSLICE) * 16 + (threadIdx.x >> 4);
    if (node >= n) return;
    const int ld = threadIdx.x & 15;
    const int base = slice * 32 + ld * 2;   // element offset within row
    const ushort_t* hb = h + base;

    float a0, a1;
    {
        const unsigned us = *(const unsigned*)(hb + (size_t)node * DIM);
        a0 = blo(us); a1 = bhi(us);
    }

    int e = offs[node];
    const int e1 = offs[node + 1];
    while (e < e1) {  // deg padded to multiple of 16 -> full 8-batches
        const int4v q0 = __builtin_nontemporal_load((const int4v*)(ebuf + e));
        const int4v q1 = __builtin_nontemporal_load((const int4v*)(ebuf + e) + 1);
        const unsigned u0 = *(const unsigned*)(hb + (size_t)q0.x * DIM);
        const unsigned u1 = *(const unsigned*)(hb + (size_t)q0.y * DIM);
        const unsigned u2 = *(const unsigned*)(hb + (size_t)q0.z * DIM);
        const unsigned u3 = *(const unsigned*)(hb + (size_t)q0.w * DIM);
        const unsigned u4 = *(const unsigned*)(hb + (size_t)q1.x * DIM);
        const unsigned u5 = *(const unsigned*)(hb + (size_t)q1.y * DIM);
        const unsigned u6 = *(const unsigned*)(hb + (size_t)q1.z * DIM);
        const unsigned u7 = *(const unsigned*)(hb + (size_t)q1.w * DIM);
        a0 += blo(u0); a1 += bhi(u0);
        a0 += blo(u1); a1 += bhi(u1);
        a0 += blo(u2); a1 += bhi(u2);
        a0 += blo(u3); a1 += bhi(u3);
        a0 += blo(u4); a1 += bhi(u4);
        a0 += blo(u5); a1 += bhi(u5);
        a0 += blo(u6); a1 += bhi(u6);
        a0 += blo(u7); a1 += bhi(u7);
        e += 8;
    }

    const float di = dinv[node];
    const float2 bv = *(const float2*)(bias + base);
    if (MODE == 0) {
        const float v0 = fmaxf(di * a0 + bv.x, 0.f);
        const float v1 = fmaxf(di * a1 + bv.y, 0.f);
        ushort_t* out = (ushort_t*)outv;
        __builtin_nontemporal_store(pack2bf(v0, v1),
                                    (unsigned*)(out + (size_t)node * DIM + base));
    } else {
        f32x2 r;
        r.x = 1.0f / (1.0f + expf(-(di * a0 + bv.x)));
        r.y = 1.0f / (1.0f + expf(-(di * a1 + bv.y)));
        float* out = (float*)outv;
        __builtin_nontemporal_store(r, (f32x2*)(out + (size_t)node * DIM + base));
    }
}

// ================= launch =================

extern "C" void kernel_launch(void* const* d_in, const int* in_sizes, int n_in,
                              void* d_out, int out_size, void* d_ws, size_t ws_size,
                              hipStream_t stream) {
    const float* x  = (const float*)d_in[0];
    const int*   ei = (const int*)d_in[1];
    const float* W1 = (const float*)d_in[2];
    const float* b1 = (const float*)d_in[3];
    const float* W2 = (const float*)d_in[4];
    const float* b2 = (const float*)d_in[5];
    float* out = (float*)d_out;

    float* wsf    = (float*)d_ws;
    float* dinv   = wsf;                            // [50048] f32
    int*   degI   = (int*)(wsf + 50048);            // [50048]
    int*   offs   = degI + 50048;                   // [50064] (uses 50001)
    int*   cursor = offs + 50064;                   // [50048]
    int*   bsum   = cursor + 50048;                 // [256]
    int*   ebuf   = bsum + 256;                     // [1600000] padded CSR (<=1.55M used), 16B-aligned
    ushort_t* Wt1 = (ushort_t*)(ebuf + 1600000);    // [65536] bf16
    ushort_t* Wt2 = Wt1 + 65536;                    // [32768] bf16
    ushort_t* h1  = Wt2 + 32768;                    // [50048*256] bf16, row 50000 = zeros
    ushort_t* agg1= h1 + (size_t)50048 * D_HID;     // [50048*256] bf16
    ushort_t* h2  = agg1 + (size_t)50048 * D_HID;   // [50048*128] bf16, row 50000 = zeros

    const int* src = ei;
    const int* dst = ei + N_EDGES;

    const int blocksN = (N_NODES + 255) / 256;  // 196
    const int blocksE = (N_EDGES + 255) / 256;

    // ---- CSR build (padded to 16) + norms ----
    hipMemsetAsync(degI, 0, N_NODES * sizeof(int), stream);
    k_count<<<blocksE, 256, 0, stream>>>(dst, degI, N_EDGES);
    k_block_sums<<<blocksN, 256, 0, stream>>>(degI, bsum, N_NODES);
    k_scan_bsums<<<1, 256, 0, stream>>>(bsum, blocksN);
    k_scan_apply<<<blocksN, 256, 0, stream>>>(degI, bsum, offs, cursor, dinv, ebuf, N_NODES);
    k_fill<<<blocksE, 256, 0, stream>>>(src, dst, cursor, ebuf, N_EDGES);

    // ---- weights + zero rows ----
    {
        const int tot = D_IN * D_HID + D_HID * D_OUT + D_HID + D_OUT;
        k_convW<<<(tot + 255) / 256, 256, 0, stream>>>(W1, W2, Wt1, Wt2,
                                                       h1 + (size_t)N_NODES * D_HID,
                                                       h2 + (size_t)N_NODES * D_OUT);
    }

    // ---- layer 1 GEMM: h1 = bf16((x @ W1) * dinv[row]) ----
    {
        dim3 g((N_NODES + 127) / 128, D_HID / 128);
        k_gemm_mfma<false><<<g, 256, 0, stream>>>(x, Wt1, dinv, h1, N_NODES, D_IN, D_HID);
    }

    // ---- aggregate 256-dim (8 slices): agg1 = bf16(relu(dinv*(sum) + b1)) ----
    {
        const int nb = (N_NODES + 15) / 16;  // 3125
        k_gather_slice<D_HID, 8, 0><<<nb * 8, 256, 0, stream>>>(
            h1, dinv, offs, ebuf, b1, agg1, N_NODES);
    }

    // ---- layer 2 GEMM: h2 = bf16((agg1 @ W2) * dinv[row]) ----
    {
        dim3 g((N_NODES + 127) / 128, D_OUT / 128);
        k_gemm_mfma<true><<<g, 256, 0, stream>>>(agg1, Wt2, dinv, h2, N_NODES, D_HID, D_OUT);
    }

    // ---- aggregate 128-dim (4 slices): out = sigmoid(dinv*(sum) + b2) ----
    {
        const int nb = (N_NODES + 15) / 16;  // 3125
        k_gather_slice<D_OUT, 4, 1><<<nb * 4, 256, 0, stream>>>(
            h2, dinv, offs, ebuf, b2, out, N_NODES);
    }
}

// Round 9
// 266.799 us; speedup vs baseline: 1.2198x; 1.2198x over previous
//
#include <hip/hip_runtime.h>
#include <hip/hip_bf16.h>
#include <math.h>

#define N_NODES 50000
#define N_EDGES 800000
#define D_IN 256
#define D_HID 256
#define D_OUT 128

typedef unsigned short ushort_t;
typedef __attribute__((ext_vector_type(8))) short bf16x8;
typedef __attribute__((ext_vector_type(4))) float f32x4;

__device__ inline ushort_t f2bf(float f) {
    __hip_bfloat16 h = __float2bfloat16(f);  // RNE
    return *reinterpret_cast<ushort_t*>(&h);
}
// bf16 pair unpack: lo = bits<<16, hi = bits&0xffff0000 (1 VALU op each)
__device__ inline float blo(unsigned u) {
    union { unsigned i; float f; } v; v.i = u << 16; return v.f;
}
__device__ inline float bhi(unsigned u) {
    union { unsigned i; float f; } v; v.i = u & 0xffff0000u; return v.f;
}
__device__ inline unsigned pack2bf(float a, float b) {
    return (unsigned)f2bf(a) | ((unsigned)f2bf(b) << 16);
}

// ================= fused: degree count + weight convert + zero rows =================
// blocks [0, 3125): count degrees (atomic). blocks [3125, 3511): convert W1/W2
// to transposed bf16 and zero the dummy rows of h1/h2.

__global__ __launch_bounds__(256) void k_count_convW(const int* __restrict__ dst,
                                                     int* __restrict__ degI,
                                                     const float* __restrict__ W1,
                                                     const float* __restrict__ W2,
                                                     ushort_t* __restrict__ Wt1,
                                                     ushort_t* __restrict__ Wt2,
                                                     ushort_t* __restrict__ h1z,
                                                     ushort_t* __restrict__ h2z) {
    const int b = blockIdx.x;
    if (b < 3125) {
        int i = b * 256 + threadIdx.x;
        if (i < N_EDGES) atomicAdd(&degI[dst[i]], 1);
    } else {
        int i = (b - 3125) * 256 + threadIdx.x;
        const int n1 = D_IN * D_HID;       // 65536
        const int n2 = D_HID * D_OUT;      // 32768
        if (i < n1) {
            int k = i / D_HID, n = i % D_HID;
            Wt1[(size_t)n * D_IN + k] = f2bf(W1[i]);
        } else if (i < n1 + n2) {
            int j = i - n1;
            int k = j / D_OUT, n = j % D_OUT;
            Wt2[(size_t)n * D_HID + k] = f2bf(W2[j]);
        } else {
            int j = i - n1 - n2;
            if (j < D_HID) h1z[j] = 0;
            else if (j < D_HID + D_OUT) h2z[j - D_HID] = 0;
        }
    }
}

// ================= self-sufficient scan over PADDED degrees (pad to 16) =================
// Each block computes its global prefix directly from degI (no bsum kernels),
// then does the block-local scan; writes offs/cursor/dinv and pads ebuf.

__global__ __launch_bounds__(256) void k_scan_apply(const int* __restrict__ degI,
                                                    int* __restrict__ offs,
                                                    int* __restrict__ cursor,
                                                    float* __restrict__ dinv,
                                                    int* __restrict__ ebuf, int n) {
    __shared__ int s[256];
    const int t = threadIdx.x;
    const int b = blockIdx.x;

    // prefix over all elements in blocks < b
    int pre = 0;
    const int lim = b * 256;
    for (int i = t; i < lim; i += 256) pre += (degI[i] + 15) & ~15;
    s[t] = pre;
    __syncthreads();
    for (int st = 128; st > 0; st >>= 1) {
        if (t < st) s[t] += s[t + st];
        __syncthreads();
    }
    const int blockoff = s[0];
    __syncthreads();

    // block-local inclusive scan of padded degs
    const int i = b * 256 + t;
    const int deg = (i < n) ? degI[i] : 0;
    const int v = (deg + 15) & ~15;
    s[t] = v;
    __syncthreads();
    for (int off = 1; off < 256; off <<= 1) {
        int u = 0;
        if (t >= off) u = s[t - off];
        __syncthreads();
        if (t >= off) s[t] += u;
        __syncthreads();
    }
    const int excl = s[t] - v + blockoff;
    if (i < n) {
        offs[i] = excl;
        cursor[i] = excl;
        dinv[i] = rsqrtf((float)(1 + deg));
        for (int p = excl + deg; p < excl + v; ++p) ebuf[p] = N_NODES;
        if (i == n - 1) offs[n] = excl + v;
    }
}

__global__ void k_fill(const int* __restrict__ src, const int* __restrict__ dst,
                       int* __restrict__ cursor, int* __restrict__ ebuf, int e) {
    int i = blockIdx.x * 256 + threadIdx.x;
    if (i < e) {
        int d = dst[i];
        int pos = atomicAdd(&cursor[d], 1);
        ebuf[pos] = src[i];
    }
}

// ================= GEMM1: 128x256 tile, 512 threads (8 waves 2x4), BK=32 =================
// h1[M,256](bf16) = (x[M,256](f32) @ Wt1[256,256]^T) * dinv[row]
// Full N=256 per block -> x is read exactly once from HBM.

__global__ __launch_bounds__(512) void k_gemm1(const float* __restrict__ A,
                                               const ushort_t* __restrict__ Bt,
                                               const float* __restrict__ dinvD,
                                               ushort_t* __restrict__ C, int M) {
    __shared__ ushort_t As[128 * 40];
    __shared__ ushort_t Bs[256 * 40];

    const int t = threadIdx.x;
    const int lane = t & 63;
    const int w = t >> 6;          // 0..7
    const int wr = w >> 2;         // 0..1
    const int wc = w & 3;          // 0..3
    const int m0 = blockIdx.x * 128;

    const int arow = t >> 2;           // 0..127
    const int acol = (t & 3) * 8;      // 0,8,16,24
    const int brow = t >> 1;           // 0..255
    const int bcol = (t & 1) * 16;     // 0,16

    f32x4 acc[4][4];
#pragma unroll
    for (int m = 0; m < 4; ++m)
#pragma unroll
        for (int n = 0; n < 4; ++n)
#pragma unroll
            for (int i = 0; i < 4; ++i) acc[m][n][i] = 0.0f;

    for (int kt = 0; kt < 256; kt += 32) {
        // stage A (128x32 f32 -> bf16)
        {
            const int gr = m0 + arow;
            float4 v0 = make_float4(0.f, 0.f, 0.f, 0.f);
            float4 v1 = make_float4(0.f, 0.f, 0.f, 0.f);
            if (gr < M) {
                const float* p = A + (size_t)gr * 256 + kt + acol;
                v0 = *(const float4*)p;
                v1 = *(const float4*)(p + 4);
            }
            ushort4 u0, u1;
            u0.x = f2bf(v0.x); u0.y = f2bf(v0.y); u0.z = f2bf(v0.z); u0.w = f2bf(v0.w);
            u1.x = f2bf(v1.x); u1.y = f2bf(v1.y); u1.z = f2bf(v1.z); u1.w = f2bf(v1.w);
            *(ushort4*)&As[arow * 40 + acol] = u0;
            *(ushort4*)&As[arow * 40 + acol + 4] = u1;
        }
        // stage B (256 cols x 32) from Bt[256][256]
        {
            const uint4* p = (const uint4*)(Bt + (size_t)brow * 256 + kt + bcol);
            uint4 v0 = p[0], v1 = p[1];
            *(uint4*)&Bs[brow * 40 + bcol] = v0;
            *(uint4*)&Bs[brow * 40 + bcol + 8] = v1;
        }
        __syncthreads();

        const int kg = (lane >> 4) * 8;
        const int lr = lane & 15;
        bf16x8 a[4], b[4];
#pragma unroll
        for (int m = 0; m < 4; ++m)
            a[m] = *(const bf16x8*)&As[(wr * 64 + m * 16 + lr) * 40 + kg];
#pragma unroll
        for (int n = 0; n < 4; ++n)
            b[n] = *(const bf16x8*)&Bs[(wc * 64 + n * 16 + lr) * 40 + kg];
#pragma unroll
        for (int m = 0; m < 4; ++m)
#pragma unroll
            for (int n = 0; n < 4; ++n)
                acc[m][n] = __builtin_amdgcn_mfma_f32_16x16x32_bf16(a[m], b[n], acc[m][n], 0, 0, 0);
        __syncthreads();
    }

    const int lr = lane & 15;
    const int rg = (lane >> 4) * 4;
#pragma unroll
    for (int m = 0; m < 4; ++m) {
        const int rb = m0 + wr * 64 + m * 16 + rg;
#pragma unroll
        for (int i = 0; i < 4; ++i) {
            const int row = rb + i;
            if (row < M) {
                const float dr = dinvD[row];
#pragma unroll
                for (int n = 0; n < 4; ++n) {
                    const int col = wc * 64 + n * 16 + lr;
                    C[(size_t)row * 256 + col] = f2bf(acc[m][n][i] * dr);
                }
            }
        }
    }
}

// ================= GEMM2: 128x128 tile, 4 waves, BK=32, A bf16 =================
// h2[M,128](bf16) = (agg1[M,256](bf16) @ Wt2[128,256]^T) * dinv[row]

__global__ __launch_bounds__(256) void k_gemm2(const ushort_t* __restrict__ A,
                                               const ushort_t* __restrict__ Bt,
                                               const float* __restrict__ dinvD,
                                               ushort_t* __restrict__ C, int M) {
    __shared__ ushort_t As[128 * 40];
    __shared__ ushort_t Bs[128 * 40];

    const int t = threadIdx.x;
    const int lane = t & 63;
    const int w = t >> 6;
    const int wr = w >> 1, wc = w & 1;
    const int m0 = blockIdx.x * 128;

    const int srow = t >> 1;
    const int scol = (t & 1) * 16;

    f32x4 acc[4][4];
#pragma unroll
    for (int m = 0; m < 4; ++m)
#pragma unroll
        for (int n = 0; n < 4; ++n)
#pragma unroll
            for (int i = 0; i < 4; ++i) acc[m][n][i] = 0.0f;

    for (int kt = 0; kt < 256; kt += 32) {
        {
            const int gr = m0 + srow;
            uint4 v0 = make_uint4(0, 0, 0, 0), v1 = make_uint4(0, 0, 0, 0);
            if (gr < M) {
                const uint4* p = (const uint4*)(A + (size_t)gr * 256 + kt + scol);
                v0 = p[0]; v1 = p[1];
            }
            *(uint4*)&As[srow * 40 + scol] = v0;
            *(uint4*)&As[srow * 40 + scol + 8] = v1;
        }
        {
            const uint4* p = (const uint4*)(Bt + (size_t)srow * 256 + kt + scol);
            uint4 v0 = p[0], v1 = p[1];
            *(uint4*)&Bs[srow * 40 + scol] = v0;
            *(uint4*)&Bs[srow * 40 + scol + 8] = v1;
        }
        __syncthreads();

        const int kg = (lane >> 4) * 8;
        const int lr = lane & 15;
        bf16x8 a[4], b[4];
#pragma unroll
        for (int m = 0; m < 4; ++m)
            a[m] = *(const bf16x8*)&As[(wr * 64 + m * 16 + lr) * 40 + kg];
#pragma unroll
        for (int n = 0; n < 4; ++n)
            b[n] = *(const bf16x8*)&Bs[(wc * 64 + n * 16 + lr) * 40 + kg];
#pragma unroll
        for (int m = 0; m < 4; ++m)
#pragma unroll
            for (int n = 0; n < 4; ++n)
                acc[m][n] = __builtin_amdgcn_mfma_f32_16x16x32_bf16(a[m], b[n], acc[m][n], 0, 0, 0);
        __syncthreads();
    }

    const int lr = lane & 15;
    const int rg = (lane >> 4) * 4;
#pragma unroll
    for (int m = 0; m < 4; ++m) {
        const int rb = m0 + wr * 64 + m * 16 + rg;
#pragma unroll
        for (int i = 0; i < 4; ++i) {
            const int row = rb + i;
            if (row < M) {
                const float dr = dinvD[row];
#pragma unroll
                for (int n = 0; n < 4; ++n) {
                    const int col = wc * 64 + n * 16 + lr;
                    C[(size_t)row * 128 + col] = f2bf(acc[m][n][i] * dr);
                }
            }
        }
    }
}

// ================= pipelined CSR gather (R5 form — known 67us) =================
// out[node] = F(dinv[node] * (h'[node] + sum_e h'[src_e]) + bias)
// Edge lists padded to multiples of 16 with the zero row. 16-edge batches with
// index prefetch; indices scalarized via readfirstlane.
// MODE 0: F = relu, bf16 out. MODE 1: F = sigmoid, f32 out.

__device__ inline void ld_idx16(const int* __restrict__ p, int* s) {
    int4 a = ((const int4*)p)[0];
    int4 b = ((const int4*)p)[1];
    int4 c = ((const int4*)p)[2];
    int4 d = ((const int4*)p)[3];
    s[0]  = __builtin_amdgcn_readfirstlane(a.x);
    s[1]  = __builtin_amdgcn_readfirstlane(a.y);
    s[2]  = __builtin_amdgcn_readfirstlane(a.z);
    s[3]  = __builtin_amdgcn_readfirstlane(a.w);
    s[4]  = __builtin_amdgcn_readfirstlane(b.x);
    s[5]  = __builtin_amdgcn_readfirstlane(b.y);
    s[6]  = __builtin_amdgcn_readfirstlane(b.z);
    s[7]  = __builtin_amdgcn_readfirstlane(b.w);
    s[8]  = __builtin_amdgcn_readfirstlane(c.x);
    s[9]  = __builtin_amdgcn_readfirstlane(c.y);
    s[10] = __builtin_amdgcn_readfirstlane(c.z);
    s[11] = __builtin_amdgcn_readfirstlane(c.w);
    s[12] = __builtin_amdgcn_readfirstlane(d.x);
    s[13] = __builtin_amdgcn_readfirstlane(d.y);
    s[14] = __builtin_amdgcn_readfirstlane(d.z);
    s[15] = __builtin_amdgcn_readfirstlane(d.w);
}

template <int DIM, int MODE>
__global__ __launch_bounds__(256) void k_gather_bf(const ushort_t* __restrict__ h,
                                                   const float* __restrict__ dinv,
                                                   const int* __restrict__ offs,
                                                   const int* __restrict__ ebuf,
                                                   const float* __restrict__ bias,
                                                   void* __restrict__ outv, int n) {
    constexpr int VEC = DIM / 64;  // 4 or 2
    const int node = (blockIdx.x * 256 + threadIdx.x) >> 6;
    const int lane = threadIdx.x & 63;
    if (node >= n) return;

    const int base = lane * VEC;
    const ushort_t* hb = h + base;
    const float di = dinv[node];

    float acc[VEC];
    if (VEC == 4) {
        uint2 u = *(const uint2*)(hb + (size_t)node * DIM);
        acc[0] = blo(u.x); acc[1] = bhi(u.x); acc[2] = blo(u.y); acc[3] = bhi(u.y);
    } else {
        unsigned u = *(const unsigned*)(hb + (size_t)node * DIM);
        acc[0] = blo(u); acc[1] = bhi(u);
    }

    int e = __builtin_amdgcn_readfirstlane(offs[node]);
    const int e1 = __builtin_amdgcn_readfirstlane(offs[node + 1]);

    int cs[16], ns[16];
    bool have = e < e1;
    if (have) ld_idx16(ebuf + e, cs);

    while (have) {
        const int en = e + 16;
        const bool hn = en < e1;
        if (VEC == 4) {
            uint2 u[16];
#pragma unroll
            for (int j = 0; j < 16; ++j)
                u[j] = *(const uint2*)(hb + (size_t)cs[j] * DIM);
            if (hn) ld_idx16(ebuf + en, ns);
#pragma unroll
            for (int j = 0; j < 16; ++j) {
                acc[0] += blo(u[j].x); acc[1] += bhi(u[j].x);
                acc[2] += blo(u[j].y); acc[3] += bhi(u[j].y);
            }
        } else {
            unsigned u[16];
#pragma unroll
            for (int j = 0; j < 16; ++j)
                u[j] = *(const unsigned*)(hb + (size_t)cs[j] * DIM);
            if (hn) ld_idx16(ebuf + en, ns);
#pragma unroll
            for (int j = 0; j < 16; ++j) {
                acc[0] += blo(u[j]); acc[1] += bhi(u[j]);
            }
        }
        e = en; have = hn;
#pragma unroll
        for (int j = 0; j < 16; ++j) cs[j] = ns[j];
    }

    if (MODE == 0) {
        ushort_t* out = (ushort_t*)outv;
        ushort4 u;
        u.x = f2bf(fmaxf(di * acc[0] + bias[base + 0], 0.f));
        u.y = f2bf(fmaxf(di * acc[1] + bias[base + 1], 0.f));
        u.z = f2bf(fmaxf(di * acc[2] + bias[base + 2], 0.f));
        u.w = f2bf(fmaxf(di * acc[3] + bias[base + 3], 0.f));
        *(ushort4*)(out + (size_t)node * DIM + base) = u;
    } else {
        float* out = (float*)outv;
        const float v0 = di * acc[0] + bias[base + 0];
        const float v1 = di * acc[1] + bias[base + 1];
        float2 r;
        r.x = 1.0f / (1.0f + expf(-v0));
        r.y = 1.0f / (1.0f + expf(-v1));
        *(float2*)(out + (size_t)node * DIM + base) = r;
    }
}

// ================= launch =================

extern "C" void kernel_launch(void* const* d_in, const int* in_sizes, int n_in,
                              void* d_out, int out_size, void* d_ws, size_t ws_size,
                              hipStream_t stream) {
    const float* x  = (const float*)d_in[0];
    const int*   ei = (const int*)d_in[1];
    const float* W1 = (const float*)d_in[2];
    const float* b1 = (const float*)d_in[3];
    const float* W2 = (const float*)d_in[4];
    const float* b2 = (const float*)d_in[5];
    float* out = (float*)d_out;

    float* wsf    = (float*)d_ws;
    float* dinv   = wsf;                            // [50048] f32
    int*   degI   = (int*)(wsf + 50048);            // [50048]
    int*   offs   = degI + 50048;                   // [50064] (uses 50001)
    int*   cursor = offs + 50064;                   // [50048]
    int*   ebuf   = cursor + 50048;                 // [1600000] padded CSR, 16B-aligned
    ushort_t* Wt1 = (ushort_t*)(ebuf + 1600000);    // [65536] bf16
    ushort_t* Wt2 = Wt1 + 65536;                    // [32768] bf16
    ushort_t* h1  = Wt2 + 32768;                    // [50048*256] bf16, row 50000 = zeros
    ushort_t* agg1= h1 + (size_t)50048 * D_HID;     // [50048*256] bf16
    ushort_t* h2  = agg1 + (size_t)50048 * D_HID;   // [50048*128] bf16, row 50000 = zeros

    const int* src = ei;
    const int* dst = ei + N_EDGES;

    const int blocksN = (N_NODES + 255) / 256;  // 196

    // 1) zero degree counters
    hipMemsetAsync(degI, 0, N_NODES * sizeof(int), stream);

    // 2) fused: degree count (blocks 0..3124) + weight convert/zero rows (3125..3510)
    k_count_convW<<<3125 + 386, 256, 0, stream>>>(dst, degI, W1, W2, Wt1, Wt2,
                                                  h1 + (size_t)N_NODES * D_HID,
                                                  h2 + (size_t)N_NODES * D_OUT);

    // 3) self-sufficient scan + dinv + ebuf padding
    k_scan_apply<<<blocksN, 256, 0, stream>>>(degI, offs, cursor, dinv, ebuf, N_NODES);

    // 4) bucket fill
    k_fill<<<(N_EDGES + 255) / 256, 256, 0, stream>>>(src, dst, cursor, ebuf, N_EDGES);

    // 5) layer 1 GEMM: h1 = bf16((x @ W1) * dinv), full-N tile (x read once)
    k_gemm1<<<(N_NODES + 127) / 128, 512, 0, stream>>>(x, Wt1, dinv, h1, N_NODES);

    // 6) aggregate 256-dim: agg1 = bf16(relu(dinv*(sum) + b1))
    k_gather_bf<D_HID, 0><<<(N_NODES * 64 + 255) / 256, 256, 0, stream>>>(
        h1, dinv, offs, ebuf, b1, agg1, N_NODES);

    // 7) layer 2 GEMM: h2 = bf16((agg1 @ W2) * dinv)
    k_gemm2<<<(N_NODES + 127) / 128, 256, 0, stream>>>(agg1, Wt2, dinv, h2, N_NODES);

    // 8) aggregate 128-dim: out = sigmoid(dinv*(sum) + b2)
    k_gather_bf<D_OUT, 1><<<(N_NODES * 64 + 255) / 256, 256, 0, stream>>>(
        h2, dinv, offs, ebuf, b2, out, N_NODES);
}

// Round 11
// 236.698 us; speedup vs baseline: 1.3749x; 1.1272x over previous
//
#include <hip/hip_runtime.h>
#include <hip/hip_bf16.h>
#include <math.h>

#define N_NODES 50000
#define N_EDGES 800000
#define D_IN 256
#define D_HID 256
#define D_OUT 128

typedef unsigned short ushort_t;
typedef unsigned char uchar_t;
typedef __attribute__((ext_vector_type(8))) short bf16x8;
typedef __attribute__((ext_vector_type(4))) float f32x4;

__device__ inline ushort_t f2bf(float f) {
    __hip_bfloat16 h = __float2bfloat16(f);  // RNE
    return *reinterpret_cast<ushort_t*>(&h);
}
// bf16 pair unpack: lo = bits<<16, hi = bits&0xffff0000 (1 VALU op each)
__device__ inline float blo(unsigned u) {
    union { unsigned i; float f; } v; v.i = u << 16; return v.f;
}
__device__ inline float bhi(unsigned u) {
    union { unsigned i; float f; } v; v.i = u & 0xffff0000u; return v.f;
}
// fp8 e4m3 encode (RNE, HW): pack one value -> low byte
__device__ inline uchar_t f2fp8(float a) {
    int w = __builtin_amdgcn_cvt_pk_fp8_f32(a, a, 0, false);
    return (uchar_t)(w & 0xff);
}
// fp8 e4m3 decode: 4 bytes -> 4 floats (2x HW pk ops). GCC-vector result: index, not .x/.y
__device__ inline void fp8x4_to_f32(unsigned u, float* o) {
    auto p0 = __builtin_amdgcn_cvt_pk_f32_fp8(u, false);  // bytes 0,1
    auto p1 = __builtin_amdgcn_cvt_pk_f32_fp8(u, true);   // bytes 2,3
    o[0] = p0[0]; o[1] = p0[1]; o[2] = p1[0]; o[3] = p1[1];
}

// ================= fused: degree count + weight convert + zero rows =================

__global__ __launch_bounds__(256) void k_count_convW(const int* __restrict__ dst,
                                                     int* __restrict__ degI,
                                                     const float* __restrict__ W1,
                                                     const float* __restrict__ W2,
                                                     ushort_t* __restrict__ Wt1,
                                                     ushort_t* __restrict__ Wt2,
                                                     uchar_t* __restrict__ h1z,
                                                     ushort_t* __restrict__ h2z) {
    const int b = blockIdx.x;
    if (b < 3125) {
        int i = b * 256 + threadIdx.x;
        if (i < N_EDGES) atomicAdd(&degI[dst[i]], 1);
    } else {
        int i = (b - 3125) * 256 + threadIdx.x;
        const int n1 = D_IN * D_HID;       // 65536
        const int n2 = D_HID * D_OUT;      // 32768
        if (i < n1) {
            int k = i / D_HID, n = i % D_HID;
            Wt1[(size_t)n * D_IN + k] = f2bf(W1[i]);
        } else if (i < n1 + n2) {
            int j = i - n1;
            int k = j / D_OUT, n = j % D_OUT;
            Wt2[(size_t)n * D_HID + k] = f2bf(W2[j]);
        } else {
            int j = i - n1 - n2;
            if (j < D_HID) h1z[j] = 0;                 // fp8 zero row
            else if (j < D_HID + D_OUT) h2z[j - D_HID] = 0;
        }
    }
}

// ================= self-sufficient scan over PADDED degrees (pad to 16) =================

__global__ __launch_bounds__(256) void k_scan_apply(const int* __restrict__ degI,
                                                    int* __restrict__ offs,
                                                    int* __restrict__ cursor,
                                                    float* __restrict__ dinv,
                                                    int* __restrict__ ebuf, int n) {
    __shared__ int s[256];
    const int t = threadIdx.x;
    const int b = blockIdx.x;

    int pre = 0;
    const int lim = b * 256;
    for (int i = t; i < lim; i += 256) pre += (degI[i] + 15) & ~15;
    s[t] = pre;
    __syncthreads();
    for (int st = 128; st > 0; st >>= 1) {
        if (t < st) s[t] += s[t + st];
        __syncthreads();
    }
    const int blockoff = s[0];
    __syncthreads();

    const int i = b * 256 + t;
    const int deg = (i < n) ? degI[i] : 0;
    const int v = (deg + 15) & ~15;
    s[t] = v;
    __syncthreads();
    for (int off = 1; off < 256; off <<= 1) {
        int u = 0;
        if (t >= off) u = s[t - off];
        __syncthreads();
        if (t >= off) s[t] += u;
        __syncthreads();
    }
    const int excl = s[t] - v + blockoff;
    if (i < n) {
        offs[i] = excl;
        cursor[i] = excl;
        dinv[i] = rsqrtf((float)(1 + deg));
        for (int p = excl + deg; p < excl + v; ++p) ebuf[p] = N_NODES;
        if (i == n - 1) offs[n] = excl + v;
    }
}

__global__ void k_fill(const int* __restrict__ src, const int* __restrict__ dst,
                       int* __restrict__ cursor, int* __restrict__ ebuf, int e) {
    int i = blockIdx.x * 256 + threadIdx.x;
    if (i < e) {
        int d = dst[i];
        int pos = atomicAdd(&cursor[d], 1);
        ebuf[pos] = src[i];
    }
}

// ================= GEMM1: 128x256 tile, 512 threads (8 waves 2x4), BK=32 =================
// h1[M,256](fp8 e4m3) = (x[M,256](f32) @ Wt1[256,256]^T) * dinv[row]

__global__ __launch_bounds__(512) void k_gemm1(const float* __restrict__ A,
                                               const ushort_t* __restrict__ Bt,
                                               const float* __restrict__ dinvD,
                                               uchar_t* __restrict__ C, int M) {
    __shared__ ushort_t As[128 * 40];
    __shared__ ushort_t Bs[256 * 40];

    const int t = threadIdx.x;
    const int lane = t & 63;
    const int w = t >> 6;
    const int wr = w >> 2;
    const int wc = w & 3;
    const int m0 = blockIdx.x * 128;

    const int arow = t >> 2;
    const int acol = (t & 3) * 8;
    const int brow = t >> 1;
    const int bcol = (t & 1) * 16;

    f32x4 acc[4][4];
#pragma unroll
    for (int m = 0; m < 4; ++m)
#pragma unroll
        for (int n = 0; n < 4; ++n)
#pragma unroll
            for (int i = 0; i < 4; ++i) acc[m][n][i] = 0.0f;

    for (int kt = 0; kt < 256; kt += 32) {
        {
            const int gr = m0 + arow;
            float4 v0 = make_float4(0.f, 0.f, 0.f, 0.f);
            float4 v1 = make_float4(0.f, 0.f, 0.f, 0.f);
            if (gr < M) {
                const float* p = A + (size_t)gr * 256 + kt + acol;
                v0 = *(const float4*)p;
                v1 = *(const float4*)(p + 4);
            }
            ushort4 u0, u1;
            u0.x = f2bf(v0.x); u0.y = f2bf(v0.y); u0.z = f2bf(v0.z); u0.w = f2bf(v0.w);
            u1.x = f2bf(v1.x); u1.y = f2bf(v1.y); u1.z = f2bf(v1.z); u1.w = f2bf(v1.w);
            *(ushort4*)&As[arow * 40 + acol] = u0;
            *(ushort4*)&As[arow * 40 + acol + 4] = u1;
        }
        {
            const uint4* p = (const uint4*)(Bt + (size_t)brow * 256 + kt + bcol);
            uint4 v0 = p[0], v1 = p[1];
            *(uint4*)&Bs[brow * 40 + bcol] = v0;
            *(uint4*)&Bs[brow * 40 + bcol + 8] = v1;
        }
        __syncthreads();

        const int kg = (lane >> 4) * 8;
        const int lr = lane & 15;
        bf16x8 a[4], b[4];
#pragma unroll
        for (int m = 0; m < 4; ++m)
            a[m] = *(const bf16x8*)&As[(wr * 64 + m * 16 + lr) * 40 + kg];
#pragma unroll
        for (int n = 0; n < 4; ++n)
            b[n] = *(const bf16x8*)&Bs[(wc * 64 + n * 16 + lr) * 40 + kg];
#pragma unroll
        for (int m = 0; m < 4; ++m)
#pragma unroll
            for (int n = 0; n < 4; ++n)
                acc[m][n] = __builtin_amdgcn_mfma_f32_16x16x32_bf16(a[m], b[n], acc[m][n], 0, 0, 0);
        __syncthreads();
    }

    const int lr = lane & 15;
    const int rg = (lane >> 4) * 4;
#pragma unroll
    for (int m = 0; m < 4; ++m) {
        const int rb = m0 + wr * 64 + m * 16 + rg;
#pragma unroll
        for (int i = 0; i < 4; ++i) {
            const int row = rb + i;
            if (row < M) {
                const float dr = dinvD[row];
#pragma unroll
                for (int n = 0; n < 4; ++n) {
                    const int col = wc * 64 + n * 16 + lr;
                    C[(size_t)row * 256 + col] = f2fp8(acc[m][n][i] * dr);
                }
            }
        }
    }
}

// ================= GEMM2: 128x128 tile, 4 waves, BK=32, A bf16 =================

__global__ __launch_bounds__(256) void k_gemm2(const ushort_t* __restrict__ A,
                                               const ushort_t* __restrict__ Bt,
                                               const float* __restrict__ dinvD,
                                               ushort_t* __restrict__ C, int M) {
    __shared__ ushort_t As[128 * 40];
    __shared__ ushort_t Bs[128 * 40];

    const int t = threadIdx.x;
    const int lane = t & 63;
    const int w = t >> 6;
    const int wr = w >> 1, wc = w & 1;
    const int m0 = blockIdx.x * 128;

    const int srow = t >> 1;
    const int scol = (t & 1) * 16;

    f32x4 acc[4][4];
#pragma unroll
    for (int m = 0; m < 4; ++m)
#pragma unroll
        for (int n = 0; n < 4; ++n)
#pragma unroll
            for (int i = 0; i < 4; ++i) acc[m][n][i] = 0.0f;

    for (int kt = 0; kt < 256; kt += 32) {
        {
            const int gr = m0 + srow;
            uint4 v0 = make_uint4(0, 0, 0, 0), v1 = make_uint4(0, 0, 0, 0);
            if (gr < M) {
                const uint4* p = (const uint4*)(A + (size_t)gr * 256 + kt + scol);
                v0 = p[0]; v1 = p[1];
            }
            *(uint4*)&As[srow * 40 + scol] = v0;
            *(uint4*)&As[srow * 40 + scol + 8] = v1;
        }
        {
            const uint4* p = (const uint4*)(Bt + (size_t)srow * 256 + kt + scol);
            uint4 v0 = p[0], v1 = p[1];
            *(uint4*)&Bs[srow * 40 + scol] = v0;
            *(uint4*)&Bs[srow * 40 + scol + 8] = v1;
        }
        __syncthreads();

        const int kg = (lane >> 4) * 8;
        const int lr = lane & 15;
        bf16x8 a[4], b[4];
#pragma unroll
        for (int m = 0; m < 4; ++m)
            a[m] = *(const bf16x8*)&As[(wr * 64 + m * 16 + lr) * 40 + kg];
#pragma unroll
        for (int n = 0; n < 4; ++n)
            b[n] = *(const bf16x8*)&Bs[(wc * 64 + n * 16 + lr) * 40 + kg];
#pragma unroll
        for (int m = 0; m < 4; ++m)
#pragma unroll
            for (int n = 0; n < 4; ++n)
                acc[m][n] = __builtin_amdgcn_mfma_f32_16x16x32_bf16(a[m], b[n], acc[m][n], 0, 0, 0);
        __syncthreads();
    }

    const int lr = lane & 15;
    const int rg = (lane >> 4) * 4;
#pragma unroll
    for (int m = 0; m < 4; ++m) {
        const int rb = m0 + wr * 64 + m * 16 + rg;
#pragma unroll
        for (int i = 0; i < 4; ++i) {
            const int row = rb + i;
            if (row < M) {
                const float dr = dinvD[row];
#pragma unroll
                for (int n = 0; n < 4; ++n) {
                    const int col = wc * 64 + n * 16 + lr;
                    C[(size_t)row * 128 + col] = f2bf(acc[m][n][i] * dr);
                }
            }
        }
    }
}

// ================= shared: 16 scalarized indices =================

__device__ inline void ld_idx16(const int* __restrict__ p, int* s) {
    int4 a = ((const int4*)p)[0];
    int4 b = ((const int4*)p)[1];
    int4 c = ((const int4*)p)[2];
    int4 d = ((const int4*)p)[3];
    s[0]  = __builtin_amdgcn_readfirstlane(a.x);
    s[1]  = __builtin_amdgcn_readfirstlane(a.y);
    s[2]  = __builtin_amdgcn_readfirstlane(a.z);
    s[3]  = __builtin_amdgcn_readfirstlane(a.w);
    s[4]  = __builtin_amdgcn_readfirstlane(b.x);
    s[5]  = __builtin_amdgcn_readfirstlane(b.y);
    s[6]  = __builtin_amdgcn_readfirstlane(b.z);
    s[7]  = __builtin_amdgcn_readfirstlane(b.w);
    s[8]  = __builtin_amdgcn_readfirstlane(c.x);
    s[9]  = __builtin_amdgcn_readfirstlane(c.y);
    s[10] = __builtin_amdgcn_readfirstlane(c.z);
    s[11] = __builtin_amdgcn_readfirstlane(c.w);
    s[12] = __builtin_amdgcn_readfirstlane(d.x);
    s[13] = __builtin_amdgcn_readfirstlane(d.y);
    s[14] = __builtin_amdgcn_readfirstlane(d.z);
    s[15] = __builtin_amdgcn_readfirstlane(d.w);
}

// ================= gather1: fp8 h1 rows -> bf16 agg1 (relu+bias) =================
// Per lane: 4 dims (1 dword per edge). HW fp8->f32 decode (cvt_pk_f32_fp8).

__global__ __launch_bounds__(256) void k_gather_fp8(const uchar_t* __restrict__ h,
                                                    const float* __restrict__ dinv,
                                                    const int* __restrict__ offs,
                                                    const int* __restrict__ ebuf,
                                                    const float* __restrict__ bias,
                                                    ushort_t* __restrict__ out, int n) {
    const int node = (blockIdx.x * 256 + threadIdx.x) >> 6;
    const int lane = threadIdx.x & 63;
    if (node >= n) return;

    const int base = lane * 4;
    const uchar_t* hb = h + base;
    const float di = dinv[node];

    float acc[4];
    {
        const unsigned u = *(const unsigned*)(hb + (size_t)node * D_HID);
        fp8x4_to_f32(u, acc);
    }

    int e = __builtin_amdgcn_readfirstlane(offs[node]);
    const int e1 = __builtin_amdgcn_readfirstlane(offs[node + 1]);

    int cs[16], ns[16];
    bool have = e < e1;
    if (have) ld_idx16(ebuf + e, cs);

    while (have) {
        const int en = e + 16;
        const bool hn = en < e1;
        unsigned u[16];
#pragma unroll
        for (int j = 0; j < 16; ++j)
            u[j] = *(const unsigned*)(hb + (size_t)cs[j] * D_HID);
        if (hn) ld_idx16(ebuf + en, ns);
#pragma unroll
        for (int j = 0; j < 16; ++j) {
            float d[4];
            fp8x4_to_f32(u[j], d);
            acc[0] += d[0]; acc[1] += d[1]; acc[2] += d[2]; acc[3] += d[3];
        }
        e = en; have = hn;
#pragma unroll
        for (int j = 0; j < 16; ++j) cs[j] = ns[j];
    }

    ushort4 o;
    o.x = f2bf(fmaxf(di * acc[0] + bias[base + 0], 0.f));
    o.y = f2bf(fmaxf(di * acc[1] + bias[base + 1], 0.f));
    o.z = f2bf(fmaxf(di * acc[2] + bias[base + 2], 0.f));
    o.w = f2bf(fmaxf(di * acc[3] + bias[base + 3], 0.f));
    *(ushort4*)(out + (size_t)node * D_HID + base) = o;
}

// ================= gather2: bf16 h2 rows -> f32 out (sigmoid+bias) =================

__global__ __launch_bounds__(256) void k_gather_bf2(const ushort_t* __restrict__ h,
                                                    const float* __restrict__ dinv,
                                                    const int* __restrict__ offs,
                                                    const int* __restrict__ ebuf,
                                                    const float* __restrict__ bias,
                                                    float* __restrict__ out, int n) {
    const int node = (blockIdx.x * 256 + threadIdx.x) >> 6;
    const int lane = threadIdx.x & 63;
    if (node >= n) return;

    const int base = lane * 2;
    const ushort_t* hb = h + base;
    const float di = dinv[node];

    float acc[2];
    {
        unsigned u = *(const unsigned*)(hb + (size_t)node * D_OUT);
        acc[0] = blo(u); acc[1] = bhi(u);
    }

    int e = __builtin_amdgcn_readfirstlane(offs[node]);
    const int e1 = __builtin_amdgcn_readfirstlane(offs[node + 1]);

    int cs[16], ns[16];
    bool have = e < e1;
    if (have) ld_idx16(ebuf + e, cs);

    while (have) {
        const int en = e + 16;
        const bool hn = en < e1;
        unsigned u[16];
#pragma unroll
        for (int j = 0; j < 16; ++j)
            u[j] = *(const unsigned*)(hb + (size_t)cs[j] * D_OUT);
        if (hn) ld_idx16(ebuf + en, ns);
#pragma unroll
        for (int j = 0; j < 16; ++j) {
            acc[0] += blo(u[j]); acc[1] += bhi(u[j]);
        }
        e = en; have = hn;
#pragma unroll
        for (int j = 0; j < 16; ++j) cs[j] = ns[j];
    }

    const float v0 = di * acc[0] + bias[base + 0];
    const float v1 = di * acc[1] + bias[base + 1];
    float2 r;
    r.x = 1.0f / (1.0f + expf(-v0));
    r.y = 1.0f / (1.0f + expf(-v1));
    *(float2*)(out + (size_t)node * D_OUT + base) = r;
}

// ================= launch =================

extern "C" void kernel_launch(void* const* d_in, const int* in_sizes, int n_in,
                              void* d_out, int out_size, void* d_ws, size_t ws_size,
                              hipStream_t stream) {
    const float* x  = (const float*)d_in[0];
    const int*   ei = (const int*)d_in[1];
    const float* W1 = (const float*)d_in[2];
    const float* b1 = (const float*)d_in[3];
    const float* W2 = (const float*)d_in[4];
    const float* b2 = (const float*)d_in[5];
    float* out = (float*)d_out;

    float* wsf    = (float*)d_ws;
    float* dinv   = wsf;                            // [50048] f32
    int*   degI   = (int*)(wsf + 50048);            // [50048]
    int*   offs   = degI + 50048;                   // [50064] (uses 50001)
    int*   cursor = offs + 50064;                   // [50048]
    int*   ebuf   = cursor + 50048;                 // [1600000] padded CSR, 16B-aligned
    ushort_t* Wt1 = (ushort_t*)(ebuf + 1600000);    // [65536] bf16
    ushort_t* Wt2 = Wt1 + 65536;                    // [32768] bf16
    uchar_t*  h1  = (uchar_t*)(Wt2 + 32768);        // [50048*256] fp8, row 50000 = zeros
    ushort_t* agg1= (ushort_t*)(h1 + (size_t)50048 * D_HID);  // [50048*256] bf16
    ushort_t* h2  = agg1 + (size_t)50048 * D_HID;   // [50048*128] bf16, row 50000 = zeros

    const int* src = ei;
    const int* dst = ei + N_EDGES;

    const int blocksN = (N_NODES + 255) / 256;  // 196

    // 1) zero degree counters
    hipMemsetAsync(degI, 0, N_NODES * sizeof(int), stream);

    // 2) fused: degree count + weight convert/zero rows
    k_count_convW<<<3125 + 386, 256, 0, stream>>>(dst, degI, W1, W2, Wt1, Wt2,
                                                  h1 + (size_t)N_NODES * D_HID,
                                                  h2 + (size_t)N_NODES * D_OUT);

    // 3) self-sufficient scan + dinv + ebuf padding
    k_scan_apply<<<blocksN, 256, 0, stream>>>(degI, offs, cursor, dinv, ebuf, N_NODES);

    // 4) bucket fill
    k_fill<<<(N_EDGES + 255) / 256, 256, 0, stream>>>(src, dst, cursor, ebuf, N_EDGES);

    // 5) layer 1 GEMM: h1 = fp8((x @ W1) * dinv), full-N tile (x read once)
    k_gemm1<<<(N_NODES + 127) / 128, 512, 0, stream>>>(x, Wt1, dinv, h1, N_NODES);

    // 6) aggregate 256-dim (fp8 payload): agg1 = bf16(relu(dinv*(sum) + b1))
    k_gather_fp8<<<(N_NODES * 64 + 255) / 256, 256, 0, stream>>>(
        h1, dinv, offs, ebuf, b1, agg1, N_NODES);

    // 7) layer 2 GEMM: h2 = bf16((agg1 @ W2) * dinv)
    k_gemm2<<<(N_NODES + 127) / 128, 256, 0, stream>>>(agg1, Wt2, dinv, h2, N_NODES);

    // 8) aggregate 128-dim: out = sigmoid(dinv*(sum) + b2)
    k_gather_bf2<<<(N_NODES * 64 + 255) / 256, 256, 0, stream>>>(
        h2, dinv, offs, ebuf, b2, out, N_NODES);
}

// Round 12
// 209.048 us; speedup vs baseline: 1.5568x; 1.1323x over previous
//
#include <hip/hip_runtime.h>
#include <hip/hip_bf16.h>
#include <math.h>

#define N_NODES 50000
#define N_EDGES 800000
#define D_IN 256
#define D_HID 256
#define D_OUT 128

typedef unsigned short ushort_t;
typedef unsigned char uchar_t;
typedef __attribute__((ext_vector_type(8))) short bf16x8;
typedef __attribute__((ext_vector_type(4))) float f32x4;

__device__ inline ushort_t f2bf(float f) {
    __hip_bfloat16 h = __float2bfloat16(f);  // RNE
    return *reinterpret_cast<ushort_t*>(&h);
}
__device__ inline float blo(unsigned u) {
    union { unsigned i; float f; } v; v.i = u << 16; return v.f;
}
__device__ inline float bhi(unsigned u) {
    union { unsigned i; float f; } v; v.i = u & 0xffff0000u; return v.f;
}
// fp8 e4m3 encode (RNE, HW): one value -> low byte
__device__ inline uchar_t f2fp8(float a) {
    int w = __builtin_amdgcn_cvt_pk_fp8_f32(a, a, 0, false);
    return (uchar_t)(w & 0xff);
}
// fp8 e4m3 decode: 4 bytes -> 4 floats (GCC-vector result: index, not .x/.y)
__device__ inline void fp8x4_to_f32(unsigned u, float* o) {
    auto p0 = __builtin_amdgcn_cvt_pk_f32_fp8(u, false);
    auto p1 = __builtin_amdgcn_cvt_pk_f32_fp8(u, true);
    o[0] = p0[0]; o[1] = p0[1]; o[2] = p1[0]; o[3] = p1[1];
}
// fp8 e4m3 decode: 2 bytes (low word) -> 2 floats
__device__ inline void fp8x2_to_f32(unsigned u, float* o) {
    auto p0 = __builtin_amdgcn_cvt_pk_f32_fp8(u, false);
    o[0] = p0[0]; o[1] = p0[1];
}

// ================= fused: degree count + weight convert + zero rows =================

__global__ __launch_bounds__(256) void k_count_convW(const int* __restrict__ dst,
                                                     int* __restrict__ degI,
                                                     const float* __restrict__ W1,
                                                     const float* __restrict__ W2,
                                                     ushort_t* __restrict__ Wt1,
                                                     ushort_t* __restrict__ Wt2,
                                                     uchar_t* __restrict__ h1z,
                                                     uchar_t* __restrict__ h2z) {
    const int b = blockIdx.x;
    if (b < 3125) {
        int i = b * 256 + threadIdx.x;
        if (i < N_EDGES) atomicAdd(&degI[dst[i]], 1);
    } else {
        int i = (b - 3125) * 256 + threadIdx.x;
        const int n1 = D_IN * D_HID;       // 65536
        const int n2 = D_HID * D_OUT;      // 32768
        if (i < n1) {
            int k = i / D_HID, n = i % D_HID;
            Wt1[(size_t)n * D_IN + k] = f2bf(W1[i]);
        } else if (i < n1 + n2) {
            int j = i - n1;
            int k = j / D_OUT, n = j % D_OUT;
            Wt2[(size_t)n * D_HID + k] = f2bf(W2[j]);
        } else {
            int j = i - n1 - n2;
            if (j < D_HID) h1z[j] = 0;                 // fp8 zero rows
            else if (j < D_HID + D_OUT) h2z[j - D_HID] = 0;
        }
    }
}

// ================= self-sufficient scan over PADDED degrees (pad to 16) =================

__global__ __launch_bounds__(256) void k_scan_apply(const int* __restrict__ degI,
                                                    int* __restrict__ offs,
                                                    int* __restrict__ cursor,
                                                    float* __restrict__ dinv,
                                                    ushort_t* __restrict__ ebuf, int n) {
    __shared__ int s[256];
    const int t = threadIdx.x;
    const int b = blockIdx.x;

    int pre = 0;
    const int lim = b * 256;
    for (int i = t; i < lim; i += 256) pre += (degI[i] + 15) & ~15;
    s[t] = pre;
    __syncthreads();
    for (int st = 128; st > 0; st >>= 1) {
        if (t < st) s[t] += s[t + st];
        __syncthreads();
    }
    const int blockoff = s[0];
    __syncthreads();

    const int i = b * 256 + t;
    const int deg = (i < n) ? degI[i] : 0;
    const int v = (deg + 15) & ~15;
    s[t] = v;
    __syncthreads();
    for (int off = 1; off < 256; off <<= 1) {
        int u = 0;
        if (t >= off) u = s[t - off];
        __syncthreads();
        if (t >= off) s[t] += u;
        __syncthreads();
    }
    const int excl = s[t] - v + blockoff;
    if (i < n) {
        offs[i] = excl;
        cursor[i] = excl;
        dinv[i] = rsqrtf((float)(1 + deg));
        for (int p = excl + deg; p < excl + v; ++p) ebuf[p] = (ushort_t)N_NODES;
        if (i == n - 1) offs[n] = excl + v;
    }
}

// ================= fused: bucket fill (ushort) + GEMM1 =================
// blocks [0, gemmBlocks): GEMM1 128x256 tile, 512 threads (8 waves 2x4), BK=32
//   h1[M,256](fp8) = (x[M,256](f32) @ Wt1^T) * dinv[row]
// blocks [gemmBlocks, ...): bucket fill — latency-bound, hides under GEMM MFMA.

__global__ __launch_bounds__(512) void k_fill_gemm1(const int* __restrict__ src,
                                                    const int* __restrict__ dst,
                                                    int* __restrict__ cursor,
                                                    ushort_t* __restrict__ ebuf,
                                                    const float* __restrict__ A,
                                                    const ushort_t* __restrict__ Bt,
                                                    const float* __restrict__ dinvD,
                                                    uchar_t* __restrict__ C,
                                                    int M, int gemmBlocks) {
    __shared__ ushort_t As[128 * 40];
    __shared__ ushort_t Bs[256 * 40];

    if (blockIdx.x >= gemmBlocks) {
        // ---- bucket fill ----
        const int i = (blockIdx.x - gemmBlocks) * 512 + threadIdx.x;
        if (i < N_EDGES) {
            const int d = dst[i];
            const int pos = atomicAdd(&cursor[d], 1);
            ebuf[pos] = (ushort_t)src[i];
        }
        return;
    }

    // ---- GEMM1 ----
    const int t = threadIdx.x;
    const int lane = t & 63;
    const int w = t >> 6;
    const int wr = w >> 2;
    const int wc = w & 3;
    const int m0 = blockIdx.x * 128;

    const int arow = t >> 2;
    const int acol = (t & 3) * 8;
    const int brow = t >> 1;
    const int bcol = (t & 1) * 16;

    f32x4 acc[4][4];
#pragma unroll
    for (int m = 0; m < 4; ++m)
#pragma unroll
        for (int n = 0; n < 4; ++n)
#pragma unroll
            for (int i = 0; i < 4; ++i) acc[m][n][i] = 0.0f;

    for (int kt = 0; kt < 256; kt += 32) {
        {
            const int gr = m0 + arow;
            float4 v0 = make_float4(0.f, 0.f, 0.f, 0.f);
            float4 v1 = make_float4(0.f, 0.f, 0.f, 0.f);
            if (gr < M) {
                const float* p = A + (size_t)gr * 256 + kt + acol;
                v0 = *(const float4*)p;
                v1 = *(const float4*)(p + 4);
            }
            ushort4 u0, u1;
            u0.x = f2bf(v0.x); u0.y = f2bf(v0.y); u0.z = f2bf(v0.z); u0.w = f2bf(v0.w);
            u1.x = f2bf(v1.x); u1.y = f2bf(v1.y); u1.z = f2bf(v1.z); u1.w = f2bf(v1.w);
            *(ushort4*)&As[arow * 40 + acol] = u0;
            *(ushort4*)&As[arow * 40 + acol + 4] = u1;
        }
        {
            const uint4* p = (const uint4*)(Bt + (size_t)brow * 256 + kt + bcol);
            uint4 v0 = p[0], v1 = p[1];
            *(uint4*)&Bs[brow * 40 + bcol] = v0;
            *(uint4*)&Bs[brow * 40 + bcol + 8] = v1;
        }
        __syncthreads();

        const int kg = (lane >> 4) * 8;
        const int lr = lane & 15;
        bf16x8 a[4], b[4];
#pragma unroll
        for (int m = 0; m < 4; ++m)
            a[m] = *(const bf16x8*)&As[(wr * 64 + m * 16 + lr) * 40 + kg];
#pragma unroll
        for (int n = 0; n < 4; ++n)
            b[n] = *(const bf16x8*)&Bs[(wc * 64 + n * 16 + lr) * 40 + kg];
#pragma unroll
        for (int m = 0; m < 4; ++m)
#pragma unroll
            for (int n = 0; n < 4; ++n)
                acc[m][n] = __builtin_amdgcn_mfma_f32_16x16x32_bf16(a[m], b[n], acc[m][n], 0, 0, 0);
        __syncthreads();
    }

    const int lr = lane & 15;
    const int rg = (lane >> 4) * 4;
#pragma unroll
    for (int m = 0; m < 4; ++m) {
        const int rb = m0 + wr * 64 + m * 16 + rg;
#pragma unroll
        for (int i = 0; i < 4; ++i) {
            const int row = rb + i;
            if (row < M) {
                const float dr = dinvD[row];
#pragma unroll
                for (int n = 0; n < 4; ++n) {
                    const int col = wc * 64 + n * 16 + lr;
                    C[(size_t)row * 256 + col] = f2fp8(acc[m][n][i] * dr);
                }
            }
        }
    }
}

// ================= GEMM2: 128x128 tile, 4 waves, BK=32, A bf16 -> C fp8 =================

__global__ __launch_bounds__(256) void k_gemm2(const ushort_t* __restrict__ A,
                                               const ushort_t* __restrict__ Bt,
                                               const float* __restrict__ dinvD,
                                               uchar_t* __restrict__ C, int M) {
    __shared__ ushort_t As[128 * 40];
    __shared__ ushort_t Bs[128 * 40];

    const int t = threadIdx.x;
    const int lane = t & 63;
    const int w = t >> 6;
    const int wr = w >> 1, wc = w & 1;
    const int m0 = blockIdx.x * 128;

    const int srow = t >> 1;
    const int scol = (t & 1) * 16;

    f32x4 acc[4][4];
#pragma unroll
    for (int m = 0; m < 4; ++m)
#pragma unroll
        for (int n = 0; n < 4; ++n)
#pragma unroll
            for (int i = 0; i < 4; ++i) acc[m][n][i] = 0.0f;

    for (int kt = 0; kt < 256; kt += 32) {
        {
            const int gr = m0 + srow;
            uint4 v0 = make_uint4(0, 0, 0, 0), v1 = make_uint4(0, 0, 0, 0);
            if (gr < M) {
                const uint4* p = (const uint4*)(A + (size_t)gr * 256 + kt + scol);
                v0 = p[0]; v1 = p[1];
            }
            *(uint4*)&As[srow * 40 + scol] = v0;
            *(uint4*)&As[srow * 40 + scol + 8] = v1;
        }
        {
            const uint4* p = (const uint4*)(Bt + (size_t)srow * 256 + kt + scol);
            uint4 v0 = p[0], v1 = p[1];
            *(uint4*)&Bs[srow * 40 + scol] = v0;
            *(uint4*)&Bs[srow * 40 + scol + 8] = v1;
        }
        __syncthreads();

        const int kg = (lane >> 4) * 8;
        const int lr = lane & 15;
        bf16x8 a[4], b[4];
#pragma unroll
        for (int m = 0; m < 4; ++m)
            a[m] = *(const bf16x8*)&As[(wr * 64 + m * 16 + lr) * 40 + kg];
#pragma unroll
        for (int n = 0; n < 4; ++n)
            b[n] = *(const bf16x8*)&Bs[(wc * 64 + n * 16 + lr) * 40 + kg];
#pragma unroll
        for (int m = 0; m < 4; ++m)
#pragma unroll
            for (int n = 0; n < 4; ++n)
                acc[m][n] = __builtin_amdgcn_mfma_f32_16x16x32_bf16(a[m], b[n], acc[m][n], 0, 0, 0);
        __syncthreads();
    }

    const int lr = lane & 15;
    const int rg = (lane >> 4) * 4;
#pragma unroll
    for (int m = 0; m < 4; ++m) {
        const int rb = m0 + wr * 64 + m * 16 + rg;
#pragma unroll
        for (int i = 0; i < 4; ++i) {
            const int row = rb + i;
            if (row < M) {
                const float dr = dinvD[row];
#pragma unroll
                for (int n = 0; n < 4; ++n) {
                    const int col = wc * 64 + n * 16 + lr;
                    C[(size_t)row * 128 + col] = f2fp8(acc[m][n][i] * dr);
                }
            }
        }
    }
}

// ================= shared: 16 scalarized ushort indices (32B, 16B-aligned) =================

__device__ inline void ld_idx16u(const ushort_t* __restrict__ p, int* s) {
    uint4 a = ((const uint4*)p)[0];
    uint4 b = ((const uint4*)p)[1];
    unsigned w0 = __builtin_amdgcn_readfirstlane(a.x);
    unsigned w1 = __builtin_amdgcn_readfirstlane(a.y);
    unsigned w2 = __builtin_amdgcn_readfirstlane(a.z);
    unsigned w3 = __builtin_amdgcn_readfirstlane(a.w);
    unsigned w4 = __builtin_amdgcn_readfirstlane(b.x);
    unsigned w5 = __builtin_amdgcn_readfirstlane(b.y);
    unsigned w6 = __builtin_amdgcn_readfirstlane(b.z);
    unsigned w7 = __builtin_amdgcn_readfirstlane(b.w);
    s[0]  = w0 & 0xffff; s[1]  = w0 >> 16;
    s[2]  = w1 & 0xffff; s[3]  = w1 >> 16;
    s[4]  = w2 & 0xffff; s[5]  = w2 >> 16;
    s[6]  = w3 & 0xffff; s[7]  = w3 >> 16;
    s[8]  = w4 & 0xffff; s[9]  = w4 >> 16;
    s[10] = w5 & 0xffff; s[11] = w5 >> 16;
    s[12] = w6 & 0xffff; s[13] = w6 >> 16;
    s[14] = w7 & 0xffff; s[15] = w7 >> 16;
}

// ================= gather1: fp8 h1 (256d) -> bf16 agg1 (relu+bias) =================

__global__ __launch_bounds__(256) void k_gather_fp8(const uchar_t* __restrict__ h,
                                                    const float* __restrict__ dinv,
                                                    const int* __restrict__ offs,
                                                    const ushort_t* __restrict__ ebuf,
                                                    const float* __restrict__ bias,
                                                    ushort_t* __restrict__ out, int n) {
    const int node = (blockIdx.x * 256 + threadIdx.x) >> 6;
    const int lane = threadIdx.x & 63;
    if (node >= n) return;

    const int base = lane * 4;
    const uchar_t* hb = h + base;
    const float di = dinv[node];

    float acc[4];
    {
        const unsigned u = *(const unsigned*)(hb + (size_t)node * D_HID);
        fp8x4_to_f32(u, acc);
    }

    int e = __builtin_amdgcn_readfirstlane(offs[node]);
    const int e1 = __builtin_amdgcn_readfirstlane(offs[node + 1]);

    int cs[16], ns[16];
    bool have = e < e1;
    if (have) ld_idx16u(ebuf + e, cs);

    while (have) {
        const int en = e + 16;
        const bool hn = en < e1;
        unsigned u[16];
#pragma unroll
        for (int j = 0; j < 16; ++j)
            u[j] = *(const unsigned*)(hb + (size_t)cs[j] * D_HID);
        if (hn) ld_idx16u(ebuf + en, ns);
#pragma unroll
        for (int j = 0; j < 16; ++j) {
            float d[4];
            fp8x4_to_f32(u[j], d);
            acc[0] += d[0]; acc[1] += d[1]; acc[2] += d[2]; acc[3] += d[3];
        }
        e = en; have = hn;
#pragma unroll
        for (int j = 0; j < 16; ++j) cs[j] = ns[j];
    }

    ushort4 o;
    o.x = f2bf(fmaxf(di * acc[0] + bias[base + 0], 0.f));
    o.y = f2bf(fmaxf(di * acc[1] + bias[base + 1], 0.f));
    o.z = f2bf(fmaxf(di * acc[2] + bias[base + 2], 0.f));
    o.w = f2bf(fmaxf(di * acc[3] + bias[base + 3], 0.f));
    *(ushort4*)(out + (size_t)node * D_HID + base) = o;
}

// ================= gather2: fp8 h2 (128d) -> f32 out (sigmoid+bias) =================
// Per lane: 2 dims = 2 fp8 bytes (ushort load), HW decode.

__global__ __launch_bounds__(256) void k_gather_fp8_2(const uchar_t* __restrict__ h,
                                                      const float* __restrict__ dinv,
                                                      const int* __restrict__ offs,
                                                      const ushort_t* __restrict__ ebuf,
                                                      const float* __restrict__ bias,
                                                      float* __restrict__ out, int n) {
    const int node = (blockIdx.x * 256 + threadIdx.x) >> 6;
    const int lane = threadIdx.x & 63;
    if (node >= n) return;

    const int base = lane * 2;
    const uchar_t* hb = h + base;
    const float di = dinv[node];

    float acc[2];
    {
        const unsigned u = *(const ushort_t*)(hb + (size_t)node * D_OUT);
        fp8x2_to_f32(u, acc);
    }

    int e = __builtin_amdgcn_readfirstlane(offs[node]);
    const int e1 = __builtin_amdgcn_readfirstlane(offs[node + 1]);

    int cs[16], ns[16];
    bool have = e < e1;
    if (have) ld_idx16u(ebuf + e, cs);

    while (have) {
        const int en = e + 16;
        const bool hn = en < e1;
        unsigned u[16];
#pragma unroll
        for (int j = 0; j < 16; ++j)
            u[j] = *(const ushort_t*)(hb + (size_t)cs[j] * D_OUT);
        if (hn) ld_idx16u(ebuf + en, ns);
#pragma unroll
        for (int j = 0; j < 16; ++j) {
            float d[2];
            fp8x2_to_f32(u[j], d);
            acc[0] += d[0]; acc[1] += d[1];
        }
        e = en; have = hn;
#pragma unroll
        for (int j = 0; j < 16; ++j) cs[j] = ns[j];
    }

    const float v0 = di * acc[0] + bias[base + 0];
    const float v1 = di * acc[1] + bias[base + 1];
    float2 r;
    r.x = 1.0f / (1.0f + expf(-v0));
    r.y = 1.0f / (1.0f + expf(-v1));
    *(float2*)(out + (size_t)node * D_OUT + base) = r;
}

// ================= launch =================

extern "C" void kernel_launch(void* const* d_in, const int* in_sizes, int n_in,
                              void* d_out, int out_size, void* d_ws, size_t ws_size,
                              hipStream_t stream) {
    const float* x  = (const float*)d_in[0];
    const int*   ei = (const int*)d_in[1];
    const float* W1 = (const float*)d_in[2];
    const float* b1 = (const float*)d_in[3];
    const float* W2 = (const float*)d_in[4];
    const float* b2 = (const float*)d_in[5];
    float* out = (float*)d_out;

    float* wsf    = (float*)d_ws;
    float* dinv   = wsf;                            // [50048] f32
    int*   degI   = (int*)(wsf + 50048);            // [50048]
    int*   offs   = degI + 50048;                   // [50064] (uses 50001)
    int*   cursor = offs + 50064;                   // [50048]
    ushort_t* ebuf= (ushort_t*)(cursor + 50048);    // [1600000] ushort padded CSR, 16B-aligned
    ushort_t* Wt1 = ebuf + 1600000;                 // [65536] bf16
    ushort_t* Wt2 = Wt1 + 65536;                    // [32768] bf16
    uchar_t*  h1  = (uchar_t*)(Wt2 + 32768);        // [50048*256] fp8, row 50000 = zeros
    ushort_t* agg1= (ushort_t*)(h1 + (size_t)50048 * D_HID);  // [50048*256] bf16
    uchar_t*  h2  = (uchar_t*)(agg1 + (size_t)50048 * D_HID); // [50048*128] fp8, row 50000 = zeros

    const int* src = ei;
    const int* dst = ei + N_EDGES;

    const int blocksN = (N_NODES + 255) / 256;  // 196

    // 1) zero degree counters
    hipMemsetAsync(degI, 0, N_NODES * sizeof(int), stream);

    // 2) fused: degree count + weight convert/zero rows
    k_count_convW<<<3125 + 386, 256, 0, stream>>>(dst, degI, W1, W2, Wt1, Wt2,
                                                  h1 + (size_t)N_NODES * D_HID,
                                                  h2 + (size_t)N_NODES * D_OUT);

    // 3) self-sufficient scan + dinv + ebuf padding
    k_scan_apply<<<blocksN, 256, 0, stream>>>(degI, offs, cursor, dinv, ebuf, N_NODES);

    // 4) fused: bucket fill + layer-1 GEMM (overlapped)
    {
        const int gemmBlocks = (N_NODES + 127) / 128;          // 391
        const int fillBlocks = (N_EDGES + 511) / 512;          // 1563
        k_fill_gemm1<<<gemmBlocks + fillBlocks, 512, 0, stream>>>(
            src, dst, cursor, ebuf, x, Wt1, dinv, h1, N_NODES, gemmBlocks);
    }

    // 5) aggregate 256-dim (fp8 payload): agg1 = bf16(relu(dinv*(sum) + b1))
    k_gather_fp8<<<(N_NODES * 64 + 255) / 256, 256, 0, stream>>>(
        h1, dinv, offs, ebuf, b1, agg1, N_NODES);

    // 6) layer 2 GEMM: h2 = fp8((agg1 @ W2) * dinv)
    k_gemm2<<<(N_NODES + 127) / 128, 256, 0, stream>>>(agg1, Wt2, dinv, h2, N_NODES);

    // 7) aggregate 128-dim (fp8 payload): out = sigmoid(dinv*(sum) + b2)
    k_gather_fp8_2<<<(N_NODES * 64 + 255) / 256, 256, 0, stream>>>(
        h2, dinv, offs, ebuf, b2, out, N_NODES);
}

// Round 13
// 204.968 us; speedup vs baseline: 1.5878x; 1.0199x over previous
//
#include <hip/hip_runtime.h>
#include <hip/hip_bf16.h>
#include <math.h>

#define N_NODES 50000
#define N_EDGES 800000
#define D_IN 256
#define D_HID 256
#define D_OUT 128

typedef unsigned short ushort_t;
typedef unsigned char uchar_t;
typedef __attribute__((ext_vector_type(8))) short bf16x8;
typedef __attribute__((ext_vector_type(4))) float f32x4;

__device__ inline ushort_t f2bf(float f) {
    __hip_bfloat16 h = __float2bfloat16(f);  // RNE
    return *reinterpret_cast<ushort_t*>(&h);
}
__device__ inline float blo(unsigned u) {
    union { unsigned i; float f; } v; v.i = u << 16; return v.f;
}
__device__ inline float bhi(unsigned u) {
    union { unsigned i; float f; } v; v.i = u & 0xffff0000u; return v.f;
}
// fp8 e4m3 encode (RNE, HW): one value -> low byte
__device__ inline uchar_t f2fp8(float a) {
    int w = __builtin_amdgcn_cvt_pk_fp8_f32(a, a, 0, false);
    return (uchar_t)(w & 0xff);
}
// fp8 e4m3 decode: 4 bytes -> 4 floats (GCC-vector result: index, not .x/.y)
__device__ inline void fp8x4_to_f32(unsigned u, float* o) {
    auto p0 = __builtin_amdgcn_cvt_pk_f32_fp8(u, false);
    auto p1 = __builtin_amdgcn_cvt_pk_f32_fp8(u, true);
    o[0] = p0[0]; o[1] = p0[1]; o[2] = p1[0]; o[3] = p1[1];
}
// fp8 e4m3 decode: 2 bytes (low word) -> 2 floats
__device__ inline void fp8x2_to_f32(unsigned u, float* o) {
    auto p0 = __builtin_amdgcn_cvt_pk_f32_fp8(u, false);
    o[0] = p0[0]; o[1] = p0[1];
}

#define NODES_PER_GRP 6250   // 8 * 6250 = 50000

// ================= fused: RANGED degree count + weight convert + zero rows =================
// blocks [0, 512): count — group g=b&7 owns dst range [g*6250,(g+1)*6250);
//   each block scans a 12500-edge slice, counts only in-range dsts (L2-local atomics).
// blocks [512, 898): convert W1/W2 to transposed bf16 + zero dummy fp8 rows.

__global__ __launch_bounds__(256) void k_count_convW(const int* __restrict__ dst,
                                                     int* __restrict__ degI,
                                                     const float* __restrict__ W1,
                                                     const float* __restrict__ W2,
                                                     ushort_t* __restrict__ Wt1,
                                                     ushort_t* __restrict__ Wt2,
                                                     uchar_t* __restrict__ h1z,
                                                     uchar_t* __restrict__ h2z) {
    const int b = blockIdx.x;
    if (b < 512) {
        const int g = b & 7;
        const int slice = b >> 3;            // 0..63
        const int lo = g * NODES_PER_GRP, hi = lo + NODES_PER_GRP;
        const int i0 = slice * 12500;        // 64*12500 = 800000
        for (int i = i0 + threadIdx.x; i < i0 + 12500; i += 256) {
            const int d = dst[i];
            if (d >= lo && d < hi) atomicAdd(&degI[d], 1);
        }
    } else {
        int i = (b - 512) * 256 + threadIdx.x;
        const int n1 = D_IN * D_HID;       // 65536
        const int n2 = D_HID * D_OUT;      // 32768
        if (i < n1) {
            int k = i / D_HID, n = i % D_HID;
            Wt1[(size_t)n * D_IN + k] = f2bf(W1[i]);
        } else if (i < n1 + n2) {
            int j = i - n1;
            int k = j / D_OUT, n = j % D_OUT;
            Wt2[(size_t)n * D_HID + k] = f2bf(W2[j]);
        } else {
            int j = i - n1 - n2;
            if (j < D_HID) h1z[j] = 0;
            else if (j < D_HID + D_OUT) h2z[j - D_HID] = 0;
        }
    }
}

// ================= self-sufficient scan over PADDED degrees (pad to 16) =================

__global__ __launch_bounds__(256) void k_scan_apply(const int* __restrict__ degI,
                                                    int* __restrict__ offs,
                                                    int* __restrict__ cursor,
                                                    float* __restrict__ dinv,
                                                    ushort_t* __restrict__ ebuf, int n) {
    __shared__ int s[256];
    const int t = threadIdx.x;
    const int b = blockIdx.x;

    int pre = 0;
    const int lim = b * 256;
    for (int i = t; i < lim; i += 256) pre += (degI[i] + 15) & ~15;
    s[t] = pre;
    __syncthreads();
    for (int st = 128; st > 0; st >>= 1) {
        if (t < st) s[t] += s[t + st];
        __syncthreads();
    }
    const int blockoff = s[0];
    __syncthreads();

    const int i = b * 256 + t;
    const int deg = (i < n) ? degI[i] : 0;
    const int v = (deg + 15) & ~15;
    s[t] = v;
    __syncthreads();
    for (int off = 1; off < 256; off <<= 1) {
        int u = 0;
        if (t >= off) u = s[t - off];
        __syncthreads();
        if (t >= off) s[t] += u;
        __syncthreads();
    }
    const int excl = s[t] - v + blockoff;
    if (i < n) {
        offs[i] = excl;
        cursor[i] = excl;
        dinv[i] = rsqrtf((float)(1 + deg));
        for (int p = excl + deg; p < excl + v; ++p) ebuf[p] = (ushort_t)N_NODES;
        if (i == n - 1) offs[n] = excl + v;
    }
}

// ================= fused: RANGED bucket fill + GEMM1 =================
// blocks [0, gemmBlocks): GEMM1 128x256 tile, 512 threads (8 waves 2x4), BK=32
//   h1[M,256](fp8) = (x[M,256](f32) @ Wt1^T) * dinv[row]
// blocks [gemmBlocks, +1600): fill — group g=(b-gemmBlocks)&7 owns dst range
//   [g*6250,(g+1)*6250); 200 slices/group x 4000 edges. Each group's cursor
//   (25KB) + ebuf region (~400KB) stay L2-local under rr dispatch -> lines
//   written back ~once instead of ping-ponged across 8 XCDs.

__global__ __launch_bounds__(512) void k_fill_gemm1(const int* __restrict__ src,
                                                    const int* __restrict__ dst,
                                                    int* __restrict__ cursor,
                                                    ushort_t* __restrict__ ebuf,
                                                    const float* __restrict__ A,
                                                    const ushort_t* __restrict__ Bt,
                                                    const float* __restrict__ dinvD,
                                                    uchar_t* __restrict__ C,
                                                    int M, int gemmBlocks) {
    __shared__ ushort_t As[128 * 40];
    __shared__ ushort_t Bs[256 * 40];

    if (blockIdx.x >= gemmBlocks) {
        const int fb = blockIdx.x - gemmBlocks;
        const int g = fb & 7;
        const int slice = fb >> 3;            // 0..199
        const int lo = g * NODES_PER_GRP, hi = lo + NODES_PER_GRP;
        const int i0 = slice * 4000;          // 200*4000 = 800000
        for (int i = i0 + threadIdx.x; i < i0 + 4000; i += 512) {
            const int d = dst[i];
            if (d >= lo && d < hi) {
                const int pos = atomicAdd(&cursor[d], 1);
                ebuf[pos] = (ushort_t)src[i];
            }
        }
        return;
    }

    // ---- GEMM1 ----
    const int t = threadIdx.x;
    const int lane = t & 63;
    const int w = t >> 6;
    const int wr = w >> 2;
    const int wc = w & 3;
    const int m0 = blockIdx.x * 128;

    const int arow = t >> 2;
    const int acol = (t & 3) * 8;
    const int brow = t >> 1;
    const int bcol = (t & 1) * 16;

    f32x4 acc[4][4];
#pragma unroll
    for (int m = 0; m < 4; ++m)
#pragma unroll
        for (int n = 0; n < 4; ++n)
#pragma unroll
            for (int i = 0; i < 4; ++i) acc[m][n][i] = 0.0f;

    for (int kt = 0; kt < 256; kt += 32) {
        {
            const int gr = m0 + arow;
            float4 v0 = make_float4(0.f, 0.f, 0.f, 0.f);
            float4 v1 = make_float4(0.f, 0.f, 0.f, 0.f);
            if (gr < M) {
                const float* p = A + (size_t)gr * 256 + kt + acol;
                v0 = *(const float4*)p;
                v1 = *(const float4*)(p + 4);
            }
            ushort4 u0, u1;
            u0.x = f2bf(v0.x); u0.y = f2bf(v0.y); u0.z = f2bf(v0.z); u0.w = f2bf(v0.w);
            u1.x = f2bf(v1.x); u1.y = f2bf(v1.y); u1.z = f2bf(v1.z); u1.w = f2bf(v1.w);
            *(ushort4*)&As[arow * 40 + acol] = u0;
            *(ushort4*)&As[arow * 40 + acol + 4] = u1;
        }
        {
            const uint4* p = (const uint4*)(Bt + (size_t)brow * 256 + kt + bcol);
            uint4 v0 = p[0], v1 = p[1];
            *(uint4*)&Bs[brow * 40 + bcol] = v0;
            *(uint4*)&Bs[brow * 40 + bcol + 8] = v1;
        }
        __syncthreads();

        const int kg = (lane >> 4) * 8;
        const int lr = lane & 15;
        bf16x8 a[4], b[4];
#pragma unroll
        for (int m = 0; m < 4; ++m)
            a[m] = *(const bf16x8*)&As[(wr * 64 + m * 16 + lr) * 40 + kg];
#pragma unroll
        for (int n = 0; n < 4; ++n)
            b[n] = *(const bf16x8*)&Bs[(wc * 64 + n * 16 + lr) * 40 + kg];
#pragma unroll
        for (int m = 0; m < 4; ++m)
#pragma unroll
            for (int n = 0; n < 4; ++n)
                acc[m][n] = __builtin_amdgcn_mfma_f32_16x16x32_bf16(a[m], b[n], acc[m][n], 0, 0, 0);
        __syncthreads();
    }

    const int lr = lane & 15;
    const int rg = (lane >> 4) * 4;
#pragma unroll
    for (int m = 0; m < 4; ++m) {
        const int rb = m0 + wr * 64 + m * 16 + rg;
#pragma unroll
        for (int i = 0; i < 4; ++i) {
            const int row = rb + i;
            if (row < M) {
                const float dr = dinvD[row];
#pragma unroll
                for (int n = 0; n < 4; ++n) {
                    const int col = wc * 64 + n * 16 + lr;
                    C[(size_t)row * 256 + col] = f2fp8(acc[m][n][i] * dr);
                }
            }
        }
    }
}

// ================= GEMM2: 128x128 tile, 4 waves, BK=32, A bf16 -> C fp8 =================

__global__ __launch_bounds__(256) void k_gemm2(const ushort_t* __restrict__ A,
                                               const ushort_t* __restrict__ Bt,
                                               const float* __restrict__ dinvD,
                                               uchar_t* __restrict__ C, int M) {
    __shared__ ushort_t As[128 * 40];
    __shared__ ushort_t Bs[128 * 40];

    const int t = threadIdx.x;
    const int lane = t & 63;
    const int w = t >> 6;
    const int wr = w >> 1, wc = w & 1;
    const int m0 = blockIdx.x * 128;

    const int srow = t >> 1;
    const int scol = (t & 1) * 16;

    f32x4 acc[4][4];
#pragma unroll
    for (int m = 0; m < 4; ++m)
#pragma unroll
        for (int n = 0; n < 4; ++n)
#pragma unroll
            for (int i = 0; i < 4; ++i) acc[m][n][i] = 0.0f;

    for (int kt = 0; kt < 256; kt += 32) {
        {
            const int gr = m0 + srow;
            uint4 v0 = make_uint4(0, 0, 0, 0), v1 = make_uint4(0, 0, 0, 0);
            if (gr < M) {
                const uint4* p = (const uint4*)(A + (size_t)gr * 256 + kt + scol);
                v0 = p[0]; v1 = p[1];
            }
            *(uint4*)&As[srow * 40 + scol] = v0;
            *(uint4*)&As[srow * 40 + scol + 8] = v1;
        }
        {
            const uint4* p = (const uint4*)(Bt + (size_t)srow * 256 + kt + scol);
            uint4 v0 = p[0], v1 = p[1];
            *(uint4*)&Bs[srow * 40 + scol] = v0;
            *(uint4*)&Bs[srow * 40 + scol + 8] = v1;
        }
        __syncthreads();

        const int kg = (lane >> 4) * 8;
        const int lr = lane & 15;
        bf16x8 a[4], b[4];
#pragma unroll
        for (int m = 0; m < 4; ++m)
            a[m] = *(const bf16x8*)&As[(wr * 64 + m * 16 + lr) * 40 + kg];
#pragma unroll
        for (int n = 0; n < 4; ++n)
            b[n] = *(const bf16x8*)&Bs[(wc * 64 + n * 16 + lr) * 40 + kg];
#pragma unroll
        for (int m = 0; m < 4; ++m)
#pragma unroll
            for (int n = 0; n < 4; ++n)
                acc[m][n] = __builtin_amdgcn_mfma_f32_16x16x32_bf16(a[m], b[n], acc[m][n], 0, 0, 0);
        __syncthreads();
    }

    const int lr = lane & 15;
    const int rg = (lane >> 4) * 4;
#pragma unroll
    for (int m = 0; m < 4; ++m) {
        const int rb = m0 + wr * 64 + m * 16 + rg;
#pragma unroll
        for (int i = 0; i < 4; ++i) {
            const int row = rb + i;
            if (row < M) {
                const float dr = dinvD[row];
#pragma unroll
                for (int n = 0; n < 4; ++n) {
                    const int col = wc * 64 + n * 16 + lr;
                    C[(size_t)row * 128 + col] = f2fp8(acc[m][n][i] * dr);
                }
            }
        }
    }
}

// ================= shared: 16 scalarized ushort indices (32B, 16B-aligned) =================

__device__ inline void ld_idx16u(const ushort_t* __restrict__ p, int* s) {
    uint4 a = ((const uint4*)p)[0];
    uint4 b = ((const uint4*)p)[1];
    unsigned w0 = __builtin_amdgcn_readfirstlane(a.x);
    unsigned w1 = __builtin_amdgcn_readfirstlane(a.y);
    unsigned w2 = __builtin_amdgcn_readfirstlane(a.z);
    unsigned w3 = __builtin_amdgcn_readfirstlane(a.w);
    unsigned w4 = __builtin_amdgcn_readfirstlane(b.x);
    unsigned w5 = __builtin_amdgcn_readfirstlane(b.y);
    unsigned w6 = __builtin_amdgcn_readfirstlane(b.z);
    unsigned w7 = __builtin_amdgcn_readfirstlane(b.w);
    s[0]  = w0 & 0xffff; s[1]  = w0 >> 16;
    s[2]  = w1 & 0xffff; s[3]  = w1 >> 16;
    s[4]  = w2 & 0xffff; s[5]  = w2 >> 16;
    s[6]  = w3 & 0xffff; s[7]  = w3 >> 16;
    s[8]  = w4 & 0xffff; s[9]  = w4 >> 16;
    s[10] = w5 & 0xffff; s[11] = w5 >> 16;
    s[12] = w6 & 0xffff; s[13] = w6 >> 16;
    s[14] = w7 & 0xffff; s[15] = w7 >> 16;
}

// ================= gather1: fp8 h1 (256d) -> bf16 agg1 (relu+bias) =================

__global__ __launch_bounds__(256) void k_gather_fp8(const uchar_t* __restrict__ h,
                                                    const float* __restrict__ dinv,
                                                    const int* __restrict__ offs,
                                                    const ushort_t* __restrict__ ebuf,
                                                    const float* __restrict__ bias,
                                                    ushort_t* __restrict__ out, int n) {
    const int node = (blockIdx.x * 256 + threadIdx.x) >> 6;
    const int lane = threadIdx.x & 63;
    if (node >= n) return;

    const int base = lane * 4;
    const uchar_t* hb = h + base;
    const float di = dinv[node];

    float acc[4];
    {
        const unsigned u = *(const unsigned*)(hb + (size_t)node * D_HID);
        fp8x4_to_f32(u, acc);
    }

    int e = __builtin_amdgcn_readfirstlane(offs[node]);
    const int e1 = __builtin_amdgcn_readfirstlane(offs[node + 1]);

    int cs[16], ns[16];
    bool have = e < e1;
    if (have) ld_idx16u(ebuf + e, cs);

    while (have) {
        const int en = e + 16;
        const bool hn = en < e1;
        unsigned u[16];
#pragma unroll
        for (int j = 0; j < 16; ++j)
            u[j] = *(const unsigned*)(hb + (size_t)cs[j] * D_HID);
        if (hn) ld_idx16u(ebuf + en, ns);
#pragma unroll
        for (int j = 0; j < 16; ++j) {
            float d[4];
            fp8x4_to_f32(u[j], d);
            acc[0] += d[0]; acc[1] += d[1]; acc[2] += d[2]; acc[3] += d[3];
        }
        e = en; have = hn;
#pragma unroll
        for (int j = 0; j < 16; ++j) cs[j] = ns[j];
    }

    ushort4 o;
    o.x = f2bf(fmaxf(di * acc[0] + bias[base + 0], 0.f));
    o.y = f2bf(fmaxf(di * acc[1] + bias[base + 1], 0.f));
    o.z = f2bf(fmaxf(di * acc[2] + bias[base + 2], 0.f));
    o.w = f2bf(fmaxf(di * acc[3] + bias[base + 3], 0.f));
    *(ushort4*)(out + (size_t)node * D_HID + base) = o;
}

// ================= gather2: fp8 h2 (128d) -> f32 out (sigmoid+bias) =================

__global__ __launch_bounds__(256) void k_gather_fp8_2(const uchar_t* __restrict__ h,
                                                      const float* __restrict__ dinv,
                                                      const int* __restrict__ offs,
                                                      const ushort_t* __restrict__ ebuf,
                                                      const float* __restrict__ bias,
                                                      float* __restrict__ out, int n) {
    const int node = (blockIdx.x * 256 + threadIdx.x) >> 6;
    const int lane = threadIdx.x & 63;
    if (node >= n) return;

    const int base = lane * 2;
    const uchar_t* hb = h + base;
    const float di = dinv[node];

    float acc[2];
    {
        const unsigned u = *(const ushort_t*)(hb + (size_t)node * D_OUT);
        fp8x2_to_f32(u, acc);
    }

    int e = __builtin_amdgcn_readfirstlane(offs[node]);
    const int e1 = __builtin_amdgcn_readfirstlane(offs[node + 1]);

    int cs[16], ns[16];
    bool have = e < e1;
    if (have) ld_idx16u(ebuf + e, cs);

    while (have) {
        const int en = e + 16;
        const bool hn = en < e1;
        unsigned u[16];
#pragma unroll
        for (int j = 0; j < 16; ++j)
            u[j] = *(const ushort_t*)(hb + (size_t)cs[j] * D_OUT);
        if (hn) ld_idx16u(ebuf + en, ns);
#pragma unroll
        for (int j = 0; j < 16; ++j) {
            float d[2];
            fp8x2_to_f32(u[j], d);
            acc[0] += d[0]; acc[1] += d[1];
        }
        e = en; have = hn;
#pragma unroll
        for (int j = 0; j < 16; ++j) cs[j] = ns[j];
    }

    const float v0 = di * acc[0] + bias[base + 0];
    const float v1 = di * acc[1] + bias[base + 1];
    float2 r;
    r.x = 1.0f / (1.0f + expf(-v0));
    r.y = 1.0f / (1.0f + expf(-v1));
    *(float2*)(out + (size_t)node * D_OUT + base) = r;
}

// ================= launch =================

extern "C" void kernel_launch(void* const* d_in, const int* in_sizes, int n_in,
                              void* d_out, int out_size, void* d_ws, size_t ws_size,
                              hipStream_t stream) {
    const float* x  = (const float*)d_in[0];
    const int*   ei = (const int*)d_in[1];
    const float* W1 = (const float*)d_in[2];
    const float* b1 = (const float*)d_in[3];
    const float* W2 = (const float*)d_in[4];
    const float* b2 = (const float*)d_in[5];
    float* out = (float*)d_out;

    float* wsf    = (float*)d_ws;
    float* dinv   = wsf;                            // [50048] f32
    int*   degI   = (int*)(wsf + 50048);            // [50048]
    int*   offs   = degI + 50048;                   // [50064] (uses 50001)
    int*   cursor = offs + 50064;                   // [50048]
    ushort_t* ebuf= (ushort_t*)(cursor + 50048);    // [1600000] ushort padded CSR, 16B-aligned
    ushort_t* Wt1 = ebuf + 1600000;                 // [65536] bf16
    ushort_t* Wt2 = Wt1 + 65536;                    // [32768] bf16
    uchar_t*  h1  = (uchar_t*)(Wt2 + 32768);        // [50048*256] fp8, row 50000 = zeros
    ushort_t* agg1= (ushort_t*)(h1 + (size_t)50048 * D_HID);  // [50048*256] bf16
    uchar_t*  h2  = (uchar_t*)(agg1 + (size_t)50048 * D_HID); // [50048*128] fp8, row 50000 = zeros

    const int* src = ei;
    const int* dst = ei + N_EDGES;

    const int blocksN = (N_NODES + 255) / 256;  // 196

    // 1) zero degree counters
    hipMemsetAsync(degI, 0, N_NODES * sizeof(int), stream);

    // 2) fused: ranged degree count (512 blocks) + weight convert/zero rows (386)
    k_count_convW<<<512 + 386, 256, 0, stream>>>(dst, degI, W1, W2, Wt1, Wt2,
                                                 h1 + (size_t)N_NODES * D_HID,
                                                 h2 + (size_t)N_NODES * D_OUT);

    // 3) self-sufficient scan + dinv + ebuf padding
    k_scan_apply<<<blocksN, 256, 0, stream>>>(degI, offs, cursor, dinv, ebuf, N_NODES);

    // 4) fused: ranged bucket fill (1600 blocks) + layer-1 GEMM (overlapped)
    {
        const int gemmBlocks = (N_NODES + 127) / 128;          // 391
        k_fill_gemm1<<<gemmBlocks + 1600, 512, 0, stream>>>(
            src, dst, cursor, ebuf, x, Wt1, dinv, h1, N_NODES, gemmBlocks);
    }

    // 5) aggregate 256-dim (fp8 payload): agg1 = bf16(relu(dinv*(sum) + b1))
    k_gather_fp8<<<(N_NODES * 64 + 255) / 256, 256, 0, stream>>>(
        h1, dinv, offs, ebuf, b1, agg1, N_NODES);

    // 6) layer 2 GEMM: h2 = fp8((agg1 @ W2) * dinv)
    k_gemm2<<<(N_NODES + 127) / 128, 256, 0, stream>>>(agg1, Wt2, dinv, h2, N_NODES);

    // 7) aggregate 128-dim (fp8 payload): out = sigmoid(dinv*(sum) + b2)
    k_gather_fp8_2<<<(N_NODES * 64 + 255) / 256, 256, 0, stream>>>(
        h2, dinv, offs, ebuf, b2, out, N_NODES);
}